// Round 12
// baseline (583.762 us; speedup 1.0000x reference)
//
#include <hip/hip_runtime.h>
#include <hip/hip_bf16.h>
#include <math.h>

#define D_ 256
#define HEADS_ 8
#define DH_ 32
#define LVLS_ 4
#define PTS_ 4
#define DFF_ 1024
#define LQ_ 900
#define B_ 16
#define S_ 13294
#define MQ (LQ_*B_)      // 14400
#define MV (S_*B_)       // 212704

typedef __attribute__((ext_vector_type(4))) float f32x4;
typedef __attribute__((ext_vector_type(8))) short bf16x8;

static __device__ inline ushort f2bf(float f) {
  __hip_bfloat16 h = __float2bfloat16(f);   // RNE
  union { __hip_bfloat16 h; ushort u; } c; c.h = h;
  return c.u;
}
static __device__ inline float bf2f(ushort u) {
  union { float f; uint u; } c; c.u = (uint)u << 16; return c.f;
}

#define GP 40   // LDS pitch in ushorts (80 B rows) for BK=32 kernels

// ---------------- value-projection GEMM: W-resident, barrier-free K-loop ----------------
// Y(bf16) = A @ W^T + bias. A:[M,256] f32; W:[256,256] f32. Block: 512 thr,
// tile 128x128 (grid 2 x ceil(M/128)). Prologue stages this block's W half
// (128x256) as bf16 into 64 KB LDS with a 16-B-granule XOR swizzle
// (idx ^= (row&7)<<3) -> optimal 8-round ds_read_b128. K-loop has NO barriers:
// A fragments stream global->reg->cvt (vmcnt-pipelined across the unrolled
// 8 iterations); W fragments are single ds_read_b128 from the resident panel.
__global__ __launch_bounds__(512) void gemm_val_kernel(
    const float* __restrict__ A, const float* __restrict__ Wm,
    const float* __restrict__ bias, ushort* __restrict__ Y, int M)
{
  __shared__ ushort Ws[128 * 256];   // 64 KB exactly
  const int tid  = threadIdx.x;
  const int lane = tid & 63;
  const int wid  = tid >> 6;          // 0..7
  const int wr   = wid >> 1;          // 0..3: 32-row band
  const int wc   = wid & 1;           // 0..1: 64-col half
  const int fr = lane & 15;
  const int hi = lane >> 4;           // 0..3
  const int fk = hi << 3;             // k offset 0,8,16,24
  const int m0 = blockIdx.y * 128, n0 = blockIdx.x * 128;

  // ---- prologue: stage W half (128 rows x 256 cols f32 -> bf16, swizzled) ----
#pragma unroll
  for (int c = 0; c < 16; ++c) {
    const int f    = c * 512 + tid;   // float4 index 0..8191
    const int row  = f >> 6;          // 64 float4 per row
    const int col4 = f & 63;
    const float4 v = *(const float4*)(Wm + (((size_t)(n0 + row)) << 8) + col4 * 4);
    ushort t4[4] __attribute__((aligned(8)));
    t4[0] = f2bf(v.x); t4[1] = f2bf(v.y); t4[2] = f2bf(v.z); t4[3] = f2bf(v.w);
    const int ui = row * 256 + ((col4 * 4) ^ ((row & 7) << 3));
    *(uint2*)&Ws[ui] = *(const uint2*)t4;
  }
  __syncthreads();   // the only barrier

  f32x4 acc[2][4];
  const f32x4 zero = {0.f, 0.f, 0.f, 0.f};
#pragma unroll
  for (int i = 0; i < 2; ++i)
#pragma unroll
    for (int j = 0; j < 4; ++j) acc[i][j] = zero;

  uint aoff[2];
#pragma unroll
  for (int i = 0; i < 2; ++i) {
    int r = m0 + wr * 32 + i * 16 + fr;
    if (r > M - 1) r = M - 1;          // clamp; write masked in epilogue
    aoff[i] = (uint)r * 256u + (uint)fk;
  }
  const int rsw = (fr & 7) << 3;       // row-XOR for W reads ((nrow&7)==(fr&7))

#pragma unroll
  for (int k0 = 0; k0 < 256; k0 += 32) {
    bf16x8 ar[2], br[4];
#pragma unroll
    for (int i = 0; i < 2; ++i) {
      const float* p = A + aoff[i] + k0;
      const float4 lo = *(const float4*)p;
      const float4 h4 = *(const float4*)(p + 4);
      ushort t[8] __attribute__((aligned(16)));
      t[0]=f2bf(lo.x); t[1]=f2bf(lo.y); t[2]=f2bf(lo.z); t[3]=f2bf(lo.w);
      t[4]=f2bf(h4.x); t[5]=f2bf(h4.y); t[6]=f2bf(h4.z); t[7]=f2bf(h4.w);
      ar[i] = *(const bf16x8*)t;
    }
#pragma unroll
    for (int j = 0; j < 4; ++j) {
      const int nrow = wc * 64 + j * 16 + fr;
      br[j] = *(const bf16x8*)&Ws[nrow * 256 + ((k0 + fk) ^ rsw)];
    }
#pragma unroll
    for (int i = 0; i < 2; ++i)
#pragma unroll
      for (int j = 0; j < 4; ++j)
        acc[i][j] = __builtin_amdgcn_mfma_f32_16x16x32_bf16(ar[i], br[j], acc[i][j], 0, 0, 0);
  }

  // epilogue: C/D layout col = lane&15, row = (lane>>4)*4 + reg; bf16 out
  const int gcolbase = n0 + wc * 64 + fr;
  float bias4[4];
#pragma unroll
  for (int j = 0; j < 4; ++j) bias4[j] = bias[gcolbase + j * 16];
#pragma unroll
  for (int i = 0; i < 2; ++i) {
    const int rb = m0 + wr * 32 + i * 16 + hi * 4;
#pragma unroll
    for (int r = 0; r < 4; ++r) {
      const int grow = rb + r;
      if (grow < M) {
#pragma unroll
        for (int j = 0; j < 4; ++j)
          Y[(size_t)grow * 256 + gcolbase + j * 16] = f2bf(acc[i][j][r] + bias4[j]);
      }
    }
  }
}

// ---------------- bf16-MFMA GEMM, 64x64 tile ----------------
// 4 waves x 32x32 quadrant. Low regs -> high occupancy; for M=14400 shapes.
__global__ __launch_bounds__(256) void gemm_bf16_64(
    const float* __restrict__ A, const float* __restrict__ X2,
    const float* __restrict__ Wm, const float* __restrict__ bias,
    float* __restrict__ Y, int M, int N, int K, int relu, int outbf)
{
  __shared__ ushort As[64 * GP];   // 5 KB
  __shared__ ushort Ws[64 * GP];   // 5 KB
  const int tid  = threadIdx.x;
  const int lane = tid & 63;
  const int wid  = tid >> 6;
  const int wr = wid >> 1, wc = wid & 1;     // wave quadrant in 2x2 (32x32 each)
  const int fr = lane & 15;
  const int fk = (lane >> 4) << 3;
  const int m0 = blockIdx.y * 64, n0 = blockIdx.x * 64;

  f32x4 acc[2][2];
  const f32x4 zero = {0.f, 0.f, 0.f, 0.f};
#pragma unroll
  for (int i = 0; i < 2; ++i)
#pragma unroll
    for (int j = 0; j < 2; ++j) acc[i][j] = zero;

  // staging: thread t owns row t>>1 of combined [A(64) | W(64)], k-half (t&1)*16
  const int srow = tid >> 1;          // 0..127
  const int skh  = (tid & 1) << 4;    // 0 or 16
  const bool isA = srow < 64;
  const float* src;
  const float* src2 = nullptr;
  ushort* dst;
  if (isA) {
    int gr = m0 + srow; if (gr > M - 1) gr = M - 1;
    src = A + (size_t)gr * K + skh;
    if (X2) src2 = X2 + (size_t)gr * K + skh;
    dst = &As[srow * GP + skh];
  } else {
    src = Wm + (size_t)(n0 + srow - 64) * K + skh;
    dst = &Ws[(srow - 64) * GP + skh];
  }

  float4 pd[4];
#pragma unroll
  for (int i2 = 0; i2 < 4; ++i2) pd[i2] = *(const float4*)(src + i2 * 4);
  if (src2) {
#pragma unroll
    for (int i2 = 0; i2 < 4; ++i2) {
      const float4 u = *(const float4*)(src2 + i2 * 4);
      pd[i2].x += u.x; pd[i2].y += u.y; pd[i2].z += u.z; pd[i2].w += u.w;
    }
  }

  for (int k0 = 0; k0 < K; k0 += 32) {
    if (k0) __syncthreads();
    ushort tmp[16] __attribute__((aligned(16)));
#pragma unroll
    for (int i2 = 0; i2 < 4; ++i2) {
      tmp[i2*4+0] = f2bf(pd[i2].x); tmp[i2*4+1] = f2bf(pd[i2].y);
      tmp[i2*4+2] = f2bf(pd[i2].z); tmp[i2*4+3] = f2bf(pd[i2].w);
    }
    *(bf16x8*)(dst)     = *(const bf16x8*)&tmp[0];
    *(bf16x8*)(dst + 8) = *(const bf16x8*)&tmp[8];
    if (k0 + 32 < K) {
      const float* s = src + k0 + 32;
#pragma unroll
      for (int i2 = 0; i2 < 4; ++i2) pd[i2] = *(const float4*)(s + i2 * 4);
      if (src2) {
        const float* s2 = src2 + k0 + 32;
#pragma unroll
        for (int i2 = 0; i2 < 4; ++i2) {
          const float4 u = *(const float4*)(s2 + i2 * 4);
          pd[i2].x += u.x; pd[i2].y += u.y; pd[i2].z += u.z; pd[i2].w += u.w;
        }
      }
    }
    __syncthreads();

    bf16x8 af[2], bf[2];
#pragma unroll
    for (int i = 0; i < 2; ++i)
      af[i] = *(const bf16x8*)&As[(wr*32 + i*16 + fr)*GP + fk];
#pragma unroll
    for (int j = 0; j < 2; ++j)
      bf[j] = *(const bf16x8*)&Ws[(wc*32 + j*16 + fr)*GP + fk];
#pragma unroll
    for (int i = 0; i < 2; ++i)
#pragma unroll
      for (int j = 0; j < 2; ++j)
        acc[i][j] = __builtin_amdgcn_mfma_f32_16x16x32_bf16(af[i], bf[j], acc[i][j], 0, 0, 0);
  }

  const int gcolbase = n0 + wc * 32 + fr;
  float bias2[2];
#pragma unroll
  for (int j = 0; j < 2; ++j) bias2[j] = bias[gcolbase + j * 16];
#pragma unroll
  for (int i = 0; i < 2; ++i) {
    const int rb = m0 + wr * 32 + i * 16 + (lane >> 4) * 4;
#pragma unroll
    for (int r = 0; r < 4; ++r) {
      const int grow = rb + r;
      if (grow < M) {
#pragma unroll
        for (int j = 0; j < 2; ++j) {
          float v = acc[i][j][r] + bias2[j];
          if (relu) v = fmaxf(v, 0.f);
          if (outbf) ((ushort*)Y)[(size_t)grow * N + gcolbase + j * 16] = f2bf(v);
          else       Y[(size_t)grow * N + gcolbase + j * 16] = v;
        }
      }
    }
  }
}

// ---------------- generic f32 GEMM: Y = act((X1 [+ X2]) @ W^T + bias) ----------------
__global__ __launch_bounds__(256) void gemm_bias_kernel(
    const float* __restrict__ X1, const float* __restrict__ X2,
    const float* __restrict__ W, const float* __restrict__ bias,
    float* __restrict__ Y, int M, int N, int K, int relu)
{
  __shared__ float As[16][64];
  __shared__ float Ws[16][64];
  const int tid = threadIdx.x;
  const int tx = tid & 15, ty = tid >> 4;
  const int m0 = blockIdx.y * 64, n0 = blockIdx.x * 64;
  float acc[4][4] = {};
  for (int k0 = 0; k0 < K; k0 += 16) {
    const int i   = tid * 4;
    const int row = i >> 4;
    const int col = i & 15;
    const int gr  = m0 + row;
    float4 v = make_float4(0.f, 0.f, 0.f, 0.f);
    if (gr < M) {
      v = *(const float4*)(X1 + (size_t)gr * K + k0 + col);
      if (X2) {
        float4 u = *(const float4*)(X2 + (size_t)gr * K + k0 + col);
        v.x += u.x; v.y += u.y; v.z += u.z; v.w += u.w;
      }
    }
    As[col+0][row] = v.x; As[col+1][row] = v.y; As[col+2][row] = v.z; As[col+3][row] = v.w;
    const float4 wv = *(const float4*)(W + (size_t)(n0 + row) * K + k0 + col);
    Ws[col+0][row] = wv.x; Ws[col+1][row] = wv.y; Ws[col+2][row] = wv.z; Ws[col+3][row] = wv.w;
    __syncthreads();
#pragma unroll
    for (int kk = 0; kk < 16; ++kk) {
      const float4 a = *(const float4*)&As[kk][ty * 4];
      const float4 w = *(const float4*)&Ws[kk][tx * 4];
      const float av[4] = {a.x, a.y, a.z, a.w};
      const float wv2[4] = {w.x, w.y, w.z, w.w};
#pragma unroll
      for (int ii = 0; ii < 4; ++ii)
#pragma unroll
        for (int jj = 0; jj < 4; ++jj)
          acc[ii][jj] = fmaf(av[ii], wv2[jj], acc[ii][jj]);
    }
    __syncthreads();
  }
  const float4 b4 = *(const float4*)(bias + n0 + tx * 4);
  const float bb[4] = {b4.x, b4.y, b4.z, b4.w};
#pragma unroll
  for (int ii = 0; ii < 4; ++ii) {
    const int gr = m0 + ty * 4 + ii;
    if (gr < M) {
      float4 o;
      o.x = acc[ii][0] + bb[0];
      o.y = acc[ii][1] + bb[1];
      o.z = acc[ii][2] + bb[2];
      o.w = acc[ii][3] + bb[3];
      if (relu) {
        o.x = fmaxf(o.x, 0.f); o.y = fmaxf(o.y, 0.f);
        o.z = fmaxf(o.z, 0.f); o.w = fmaxf(o.w, 0.f);
      }
      *(float4*)(Y + (size_t)gr * N + n0 + tx * 4) = o;
    }
  }
}

// ---------------- self-attention: MFMA flash (swapped QK^T), bf16 ----------------
#define QB 64
#define KB 64
#define KP 40   // Ks / P pitch (ushort)
#define VP 72   // Vt pitch (ushort)
__global__ __launch_bounds__(256) void attn_mfma_kernel(
    const float* __restrict__ QK, const float* __restrict__ V,
    float* __restrict__ O)
{
  __shared__ ushort Ks[KB * KP];
  __shared__ ushort Vt[DH_ * VP];
  __shared__ ushort Pl[4][16 * KP];
  const int tid  = threadIdx.x;
  const int lane = tid & 63;
  const int w    = tid >> 6;
  const int bh = blockIdx.y;
  const int h  = bh & (HEADS_ - 1);
  const int b  = bh >> 3;
  const int q0 = blockIdx.x * QB;
  const int lq = lane & 15;
  const int lg = lane >> 4;
  const float scale = 0.17677669529663687f;
  const f32x4 zero4 = {0.f, 0.f, 0.f, 0.f};

  bf16x8 qf;
  {
    int qg = q0 + w * 16 + lq; if (qg > LQ_ - 1) qg = LQ_ - 1;
    const float* qp = QK + ((size_t)qg * B_ + b) * 512 + h * DH_ + lg * 8;
    const float4 a = *(const float4*)qp;
    const float4 c = *(const float4*)(qp + 4);
    ushort t[8] __attribute__((aligned(16)));
    t[0]=f2bf(a.x*scale); t[1]=f2bf(a.y*scale); t[2]=f2bf(a.z*scale); t[3]=f2bf(a.w*scale);
    t[4]=f2bf(c.x*scale); t[5]=f2bf(c.y*scale); t[6]=f2bf(c.z*scale); t[7]=f2bf(c.w*scale);
    qf = *(const bf16x8*)t;
  }

  float mrow = -1e30f, srow = 0.f;
  f32x4 oacc[2]; oacc[0] = zero4; oacc[1] = zero4;

  const int nkt = (LQ_ + KB - 1) / KB;   // 15
  for (int t = 0; t < nkt; ++t) {
    const int k0 = t * KB;
    const int klen = (LQ_ - k0) < KB ? (LQ_ - k0) : KB;
    if (t) __syncthreads();
    {
      const int kk  = tid >> 2;
      const int dh0 = (tid & 3) * 8;
      ushort kb[8] __attribute__((aligned(16)));
      ushort vb[8];
      if (kk < klen) {
        const size_t row = (size_t)(k0 + kk) * B_ + b;
        const float* kp = QK + row * 512 + 256 + h * DH_ + dh0;
        const float* vp = V  + row * 256 + h * DH_ + dh0;
        const float4 k1 = *(const float4*)kp;
        const float4 k2 = *(const float4*)(kp + 4);
        const float4 v1 = *(const float4*)vp;
        const float4 v2 = *(const float4*)(vp + 4);
        kb[0]=f2bf(k1.x); kb[1]=f2bf(k1.y); kb[2]=f2bf(k1.z); kb[3]=f2bf(k1.w);
        kb[4]=f2bf(k2.x); kb[5]=f2bf(k2.y); kb[6]=f2bf(k2.z); kb[7]=f2bf(k2.w);
        vb[0]=f2bf(v1.x); vb[1]=f2bf(v1.y); vb[2]=f2bf(v1.z); vb[3]=f2bf(v1.w);
        vb[4]=f2bf(v2.x); vb[5]=f2bf(v2.y); vb[6]=f2bf(v2.z); vb[7]=f2bf(v2.w);
      } else {
#pragma unroll
        for (int j = 0; j < 8; ++j) { kb[j] = 0; vb[j] = 0; }
      }
      *(bf16x8*)&Ks[kk * KP + dh0] = *(const bf16x8*)kb;
#pragma unroll
      for (int j = 0; j < 8; ++j) Vt[(dh0 + j) * VP + kk] = vb[j];
    }
    __syncthreads();

    f32x4 sc[4];
#pragma unroll
    for (int j = 0; j < 4; ++j) {
      const bf16x8 kf = *(const bf16x8*)&Ks[(j * 16 + lq) * KP + lg * 8];
      sc[j] = __builtin_amdgcn_mfma_f32_16x16x32_bf16(kf, qf, zero4, 0, 0, 0);
    }
    if (klen < KB) {
#pragma unroll
      for (int j = 0; j < 4; ++j)
#pragma unroll
        for (int r = 0; r < 4; ++r)
          if (j * 16 + lg * 4 + r >= klen) sc[j][r] = -1e30f;
    }
    float tmax = -1e30f;
#pragma unroll
    for (int j = 0; j < 4; ++j)
#pragma unroll
      for (int r = 0; r < 4; ++r) tmax = fmaxf(tmax, sc[j][r]);
    tmax = fmaxf(tmax, __shfl_xor(tmax, 16, 64));
    tmax = fmaxf(tmax, __shfl_xor(tmax, 32, 64));
    const float mnew = fmaxf(mrow, tmax);
    const float cfac = __expf(mrow - mnew);
    mrow = mnew;
    float tsum = 0.f;
#pragma unroll
    for (int j = 0; j < 4; ++j)
#pragma unroll
      for (int r = 0; r < 4; ++r) {
        const float p = __expf(sc[j][r] - mnew);
        sc[j][r] = p; tsum += p;
      }
    tsum += __shfl_xor(tsum, 16, 64);
    tsum += __shfl_xor(tsum, 32, 64);
    srow = srow * cfac + tsum;
#pragma unroll
    for (int j = 0; j < 4; ++j) {
      const uint lo = (uint)f2bf(sc[j][0]) | ((uint)f2bf(sc[j][1]) << 16);
      const uint hi = (uint)f2bf(sc[j][2]) | ((uint)f2bf(sc[j][3]) << 16);
      *(uint*)&Pl[w][lq * KP + j * 16 + lg * 4]     = lo;
      *(uint*)&Pl[w][lq * KP + j * 16 + lg * 4 + 2] = hi;
    }
    float crow[4];
#pragma unroll
    for (int r = 0; r < 4; ++r) crow[r] = __shfl(cfac, lg * 4 + r, 64);
#pragma unroll
    for (int nt = 0; nt < 2; ++nt)
#pragma unroll
      for (int r = 0; r < 4; ++r) oacc[nt][r] *= crow[r];
#pragma unroll
    for (int ks = 0; ks < 2; ++ks) {
      const bf16x8 pf = *(const bf16x8*)&Pl[w][lq * KP + ks * 32 + lg * 8];
#pragma unroll
      for (int nt = 0; nt < 2; ++nt) {
        const bf16x8 vf = *(const bf16x8*)&Vt[(nt * 16 + lq) * VP + ks * 32 + lg * 8];
        oacc[nt] = __builtin_amdgcn_mfma_f32_16x16x32_bf16(pf, vf, oacc[nt], 0, 0, 0);
      }
    }
  }
  float sinv[4];
#pragma unroll
  for (int r = 0; r < 4; ++r) {
    const float sr = __shfl(srow, lg * 4 + r, 64);
    sinv[r] = 1.f / sr;
  }
#pragma unroll
  for (int r = 0; r < 4; ++r) {
    const int qg = q0 + w * 16 + lg * 4 + r;
    if (qg < LQ_) {
      float* op = O + ((size_t)qg * B_ + b) * 256 + h * DH_;
      op[lq]      = oacc[0][r] * sinv[r];
      op[16 + lq] = oacc[1][r] * sinv[r];
    }
  }
}

// ---------------- residual + LayerNorm: Y = LN(X + R) * g + b ----------------
__global__ __launch_bounds__(256) void ln_kernel(
    const float* __restrict__ X, const float* __restrict__ R,
    const float* __restrict__ g, const float* __restrict__ be,
    float* __restrict__ Y)
{
  const int row = blockIdx.x;
  const int t = threadIdx.x;
  const size_t idx = (size_t)row * D_ + t;
  const float v = X[idx] + R[idx];
  __shared__ float red[4];
  const int wid = t >> 6, lane = t & 63;

  float sum = v;
#pragma unroll
  for (int o = 32; o > 0; o >>= 1) sum += __shfl_xor(sum, o, 64);
  if (lane == 0) red[wid] = sum;
  __syncthreads();
  const float mean = (red[0] + red[1] + red[2] + red[3]) * (1.f / D_);
  const float d = v - mean;
  float sq = d * d;
#pragma unroll
  for (int o = 32; o > 0; o >>= 1) sq += __shfl_xor(sq, o, 64);
  __syncthreads();
  if (lane == 0) red[wid] = sq;
  __syncthreads();
  const float var = (red[0] + red[1] + red[2] + red[3]) * (1.f / D_);
  Y[idx] = d * rsqrtf(var + 1e-5f) * g[t] + be[t];
}

// ---------------- MSDeformAttn sampling (bf16 value; 4 threads per (q,b,h)) ----------------
__global__ __launch_bounds__(256) void msdeform_kernel(
    const float* __restrict__ refp, const float* __restrict__ offb,
    const float* __restrict__ awb, const ushort* __restrict__ value,
    float* __restrict__ out)
{
  const int t  = blockIdx.x * 256 + threadIdx.x;   // < MQ*HEADS_*4
  const int dq = t & 3;            // dh quarter: 8 floats
  const int h  = (t >> 2) & 7;
  const int u  = t >> 5;           // b*LQ_ + q
  const int b  = u / LQ_;
  const int q  = u - b * LQ_;
  const int r  = q * B_ + b;

  float aw[LVLS_ * PTS_];
  const float* ap = awb + (size_t)r * 128 + h * 16;
  float m = -1e30f;
#pragma unroll
  for (int i = 0; i < 16; ++i) { aw[i] = ap[i]; m = fmaxf(m, aw[i]); }
  float s = 0.f;
#pragma unroll
  for (int i = 0; i < 16; ++i) { aw[i] = __expf(aw[i] - m); s += aw[i]; }
  const float inv = 1.f / s;
#pragma unroll
  for (int i = 0; i < 16; ++i) aw[i] *= inv;

  float o[8] = {};
  const int HH[4] = {100, 50, 25, 13};
  const int WW[4] = {100, 50, 25, 13};
  const int ST[4] = {0, 10000, 12500, 13125};
  const float* orow = offb + (size_t)r * 256 + h * (LVLS_ * PTS_ * 2);
  const int dh0 = h * DH_ + dq * 8;

  for (int l = 0; l < LVLS_; ++l) {
    const float4 rf = *(const float4*)(refp + (((size_t)q * B_ + b) * LVLS_ + l) * 4);
    const int W_ = WW[l], H_ = HH[l], s0 = ST[l];
    for (int p = 0; p < PTS_; ++p) {
      const float ox = orow[(l * PTS_ + p) * 2 + 0];
      const float oy = orow[(l * PTS_ + p) * 2 + 1];
      const float lx = rf.x + ox * 0.125f * rf.z;
      const float ly = rf.y + oy * 0.125f * rf.w;
      const float x = lx * W_ - 0.5f;
      const float y = ly * H_ - 0.5f;
      const float x0f = floorf(x), y0f = floorf(y);
      const float wx = x - x0f, wy = y - y0f;
      const int x0 = (int)x0f, y0 = (int)y0f;
      const float a = aw[l * PTS_ + p];
      const float cw[4] = {(1.f - wx) * (1.f - wy) * a, wx * (1.f - wy) * a,
                           (1.f - wx) * wy * a,         wx * wy * a};
      const int cx[4] = {x0, x0 + 1, x0, x0 + 1};
      const int cy[4] = {y0, y0, y0 + 1, y0 + 1};
#pragma unroll
      for (int c = 0; c < 4; ++c) {
        const int xi = cx[c], yi = cy[c];
        if (xi >= 0 && xi < W_ && yi >= 0 && yi < H_) {
          const ushort* vp = value + ((size_t)(s0 + yi * W_ + xi) * B_ + b) * 256 + dh0;
          const float w = cw[c];
          const bf16x8 vv = *(const bf16x8*)vp;   // 16 B
#pragma unroll
          for (int j = 0; j < 8; ++j)
            o[j] = fmaf(w, bf2f(((const ushort*)&vv)[j]), o[j]);
        }
      }
    }
  }
  float* op = out + (size_t)r * 256 + dh0;
  float4 x1; x1.x = o[0]; x1.y = o[1]; x1.z = o[2]; x1.w = o[3];
  float4 x2; x2.x = o[4]; x2.y = o[5]; x2.z = o[6]; x2.w = o[7];
  *(float4*)op = x1;
  *(float4*)(op + 4) = x2;
}

extern "C" void kernel_launch(void* const* d_in, const int* in_sizes, int n_in,
                              void* d_out, int out_size, void* d_ws, size_t ws_size,
                              hipStream_t stream) {
  const float* tgt       = (const float*)d_in[0];
  const float* pos       = (const float*)d_in[1];
  const float* refp      = (const float*)d_in[2];
  const float* memory    = (const float*)d_in[3];
  const float* in_proj_w = (const float*)d_in[6];
  const float* in_proj_b = (const float*)d_in[7];
  const float* sa_out_w  = (const float*)d_in[8];
  const float* sa_out_b  = (const float*)d_in[9];
  const float* off_w     = (const float*)d_in[10];
  const float* off_b     = (const float*)d_in[11];
  const float* aw_w      = (const float*)d_in[12];
  const float* aw_b      = (const float*)d_in[13];
  const float* val_w     = (const float*)d_in[14];
  const float* val_b     = (const float*)d_in[15];
  const float* ca_out_w  = (const float*)d_in[16];
  const float* ca_out_b  = (const float*)d_in[17];
  const float* lin1_w    = (const float*)d_in[18];
  const float* lin1_b    = (const float*)d_in[19];
  const float* lin2_w    = (const float*)d_in[20];
  const float* lin2_b    = (const float*)d_in[21];
  const float* n1g = (const float*)d_in[22];
  const float* n1b = (const float*)d_in[23];
  const float* n2g = (const float*)d_in[24];
  const float* n2b = (const float*)d_in[25];
  const float* n3g = (const float*)d_in[26];
  const float* n3b = (const float*)d_in[27];

  float* ws = (float*)d_ws;
  float* QK    = ws;                               // MQ*512
  float* Vb    = QK   + (size_t)MQ * 512;          // MQ*256
  float* Cb    = Vb   + (size_t)MQ * 256;          // MQ*256
  float* Db    = Cb   + (size_t)MQ * 256;          // MQ*256
  float* tgt1  = Db   + (size_t)MQ * 256;          // MQ*256
  float* tgt2  = tgt1 + (size_t)MQ * 256;          // MQ*256
  float* big   = tgt2 + (size_t)MQ * 256;          // max(MV*128, MQ*1024) floats
  ushort* value = (ushort*)big;                    // MV*256 bf16
  float* mid   = big;   // FFN mid aliases value region (disjoint lifetimes)

  const dim3 blk(256);
  const int gy_q = (MQ + 63) / 64;        // 225
  const int gy_v128 = (MV + 127) / 128;   // 1662
  const int qtiles = (LQ_ + QB - 1) / QB; // 15

  // 1) Q,K projections (input tgt+pos), N=512 — bf16 MFMA 64-tile
  gemm_bf16_64<<<dim3(8, gy_q), blk, 0, stream>>>(tgt, pos, in_proj_w, in_proj_b, QK, MQ, 512, D_, 0, 0);
  // 2) V projection (input tgt), N=256 — bf16 MFMA 64-tile
  gemm_bf16_64<<<dim3(4, gy_q), blk, 0, stream>>>(tgt, nullptr, in_proj_w + 512 * D_, in_proj_b + 512, Vb, MQ, 256, D_, 0, 0);
  // 3) self-attention — bf16 MFMA flash
  attn_mfma_kernel<<<dim3(qtiles, B_ * HEADS_), blk, 0, stream>>>(QK, Vb, Cb);
  // 4) SA out proj — bf16 MFMA 64-tile
  gemm_bf16_64<<<dim3(4, gy_q), blk, 0, stream>>>(Cb, nullptr, sa_out_w, sa_out_b, Db, MQ, 256, D_, 0, 0);
  // 5) tgt1 = LN(tgt + sa; norm2)
  ln_kernel<<<MQ, blk, 0, stream>>>(tgt, Db, n2g, n2b, tgt1);
  // 6) value projection over memory — W-resident barrier-free bf16 GEMM
  gemm_val_kernel<<<dim3(2, gy_v128), dim3(512), 0, stream>>>(memory, val_w, val_b, value, MV);
  // 7) sampling offsets (input tgt1+pos) — f32 for position precision
  gemm_bias_kernel<<<dim3(4, gy_q), blk, 0, stream>>>(tgt1, pos, off_w, off_b, QK, MQ, 256, D_, 0);
  // 8) attention-weight logits — bf16 64-tile (softmax-tolerant)
  gemm_bf16_64<<<dim3(2, gy_q), blk, 0, stream>>>(tgt1, pos, aw_w, aw_b, Vb, MQ, 128, D_, 0, 0);
  // 9) deformable sampling -> Cb  (bf16 value gather)
  msdeform_kernel<<<(MQ * HEADS_ * 4 + 255) / 256, blk, 0, stream>>>(refp, QK, Vb, value, Cb);
  // 10) CA out proj — bf16 MFMA 64-tile
  gemm_bf16_64<<<dim3(4, gy_q), blk, 0, stream>>>(Cb, nullptr, ca_out_w, ca_out_b, Db, MQ, 256, D_, 0, 0);
  // 11) tgt2 = LN(tgt1 + ca; norm1)
  ln_kernel<<<MQ, blk, 0, stream>>>(tgt1, Db, n1g, n1b, tgt2);
  // 12) FFN lin1 + relu -> mid — bf16 MFMA 64-tile
  gemm_bf16_64<<<dim3(16, gy_q), blk, 0, stream>>>(tgt2, nullptr, lin1_w, lin1_b, mid, MQ, DFF_, D_, 1, 0);
  // 13) FFN lin2 -> Db — bf16 MFMA 64-tile (K=1024)
  gemm_bf16_64<<<dim3(4, gy_q), blk, 0, stream>>>(mid, nullptr, lin2_w, lin2_b, Db, MQ, 256, DFF_, 0, 0);
  // 14) out = LN(tgt2 + ffn; norm3)
  ln_kernel<<<MQ, blk, 0, stream>>>(tgt2, Db, n3g, n3b, (float*)d_out);
}

// Round 13
// 528.336 us; speedup vs baseline: 1.1049x; 1.1049x over previous
//
#include <hip/hip_runtime.h>
#include <hip/hip_bf16.h>
#include <math.h>

#define D_ 256
#define HEADS_ 8
#define DH_ 32
#define LVLS_ 4
#define PTS_ 4
#define DFF_ 1024
#define LQ_ 900
#define B_ 16
#define S_ 13294
#define MQ (LQ_*B_)      // 14400
#define MV (S_*B_)       // 212704

typedef __attribute__((ext_vector_type(4))) float f32x4;
typedef __attribute__((ext_vector_type(8))) short bf16x8;

static __device__ inline ushort f2bf(float f) {
  __hip_bfloat16 h = __float2bfloat16(f);   // RNE
  union { __hip_bfloat16 h; ushort u; } c; c.h = h;
  return c.u;
}
static __device__ inline float bf2f(ushort u) {
  union { float f; uint u; } c; c.u = (uint)u << 16; return c.f;
}

#define GP 40   // LDS pitch in ushorts (80 B rows)

// ---------------- bf16-MFMA GEMM, 128x128 tile, 8 waves, BK=32 ----------------
// R10 variant — best measured on the value projection (136 us).
// Y = act(A @ W^T + bias). A:[M,K] f32; W:[N,K] f32; Y f32 or bf16.
__global__ __launch_bounds__(512) void gemm_bf16_512(
    const float* __restrict__ A, const float* __restrict__ Wm,
    const float* __restrict__ bias, float* __restrict__ Y,
    int M, int N, int K, int relu, int outbf)
{
  __shared__ ushort As[128 * GP];   // 10 KB
  __shared__ ushort Ws[128 * GP];   // 10 KB
  const int tid  = threadIdx.x;
  const int lane = tid & 63;
  const int wid  = tid >> 6;          // 0..7
  const int wr   = wid >> 1;          // 0..3: 32-row band
  const int wc   = wid & 1;           // 0..1: 64-col half
  const int fr = lane & 15;
  const int fk = (lane >> 4) << 3;
  const int m0 = blockIdx.y * 128, n0 = blockIdx.x * 128;

  f32x4 acc[2][4];
  const f32x4 zero = {0.f, 0.f, 0.f, 0.f};
#pragma unroll
  for (int i = 0; i < 2; ++i)
#pragma unroll
    for (int j = 0; j < 4; ++j) acc[i][j] = zero;

  // staging: thread t owns row t>>2 (0..127), k-slice (t&3)*8 (8 floats)
  const int srow = tid >> 2;
  const int skh  = (tid & 3) << 3;
  int agr = m0 + srow; if (agr > M - 1) agr = M - 1;
  const float* apb = A  + (size_t)agr * K + skh;
  const float* wpb = Wm + (size_t)(n0 + srow) * K + skh;

  float4 pa[2], pw[2];
  pa[0] = *(const float4*)(apb);     pa[1] = *(const float4*)(apb + 4);
  pw[0] = *(const float4*)(wpb);     pw[1] = *(const float4*)(wpb + 4);

  for (int k0 = 0; k0 < K; k0 += 32) {
    if (k0) __syncthreads();
    ushort tmp[8] __attribute__((aligned(16)));
    tmp[0]=f2bf(pa[0].x); tmp[1]=f2bf(pa[0].y); tmp[2]=f2bf(pa[0].z); tmp[3]=f2bf(pa[0].w);
    tmp[4]=f2bf(pa[1].x); tmp[5]=f2bf(pa[1].y); tmp[6]=f2bf(pa[1].z); tmp[7]=f2bf(pa[1].w);
    *(bf16x8*)&As[srow*GP + skh] = *(const bf16x8*)tmp;
    tmp[0]=f2bf(pw[0].x); tmp[1]=f2bf(pw[0].y); tmp[2]=f2bf(pw[0].z); tmp[3]=f2bf(pw[0].w);
    tmp[4]=f2bf(pw[1].x); tmp[5]=f2bf(pw[1].y); tmp[6]=f2bf(pw[1].z); tmp[7]=f2bf(pw[1].w);
    *(bf16x8*)&Ws[srow*GP + skh] = *(const bf16x8*)tmp;
    if (k0 + 32 < K) {
      const float* ap = apb + k0 + 32;
      const float* wp = wpb + k0 + 32;
      pa[0] = *(const float4*)(ap);  pa[1] = *(const float4*)(ap + 4);
      pw[0] = *(const float4*)(wp);  pw[1] = *(const float4*)(wp + 4);
    }
    __syncthreads();

    bf16x8 ar[2], br[4];
#pragma unroll
    for (int i = 0; i < 2; ++i)
      ar[i] = *(const bf16x8*)&As[(wr*32 + i*16 + fr)*GP + fk];
#pragma unroll
    for (int j = 0; j < 4; ++j)
      br[j] = *(const bf16x8*)&Ws[(wc*64 + j*16 + fr)*GP + fk];
#pragma unroll
    for (int i = 0; i < 2; ++i)
#pragma unroll
      for (int j = 0; j < 4; ++j)
        acc[i][j] = __builtin_amdgcn_mfma_f32_16x16x32_bf16(ar[i], br[j], acc[i][j], 0, 0, 0);
  }

  // epilogue: C/D layout col = lane&15, row = (lane>>4)*4 + reg
  const int gcolbase = n0 + wc * 64 + fr;
  float bias4[4];
#pragma unroll
  for (int j = 0; j < 4; ++j) bias4[j] = bias[gcolbase + j * 16];
#pragma unroll
  for (int i = 0; i < 2; ++i) {
    const int rb = m0 + wr * 32 + i * 16 + (lane >> 4) * 4;
#pragma unroll
    for (int r = 0; r < 4; ++r) {
      const int grow = rb + r;
      if (grow < M) {
#pragma unroll
        for (int j = 0; j < 4; ++j) {
          float v = acc[i][j][r] + bias4[j];
          if (relu) v = fmaxf(v, 0.f);
          if (outbf) ((ushort*)Y)[(size_t)grow * N + gcolbase + j * 16] = f2bf(v);
          else       Y[(size_t)grow * N + gcolbase + j * 16] = v;
        }
      }
    }
  }
}

// ---------------- bf16-MFMA GEMM, 64x64 tile ----------------
// 4 waves x 32x32 quadrant. Low regs -> high occupancy; for M=14400 shapes.
__global__ __launch_bounds__(256) void gemm_bf16_64(
    const float* __restrict__ A, const float* __restrict__ X2,
    const float* __restrict__ Wm, const float* __restrict__ bias,
    float* __restrict__ Y, int M, int N, int K, int relu, int outbf)
{
  __shared__ ushort As[64 * GP];   // 5 KB
  __shared__ ushort Ws[64 * GP];   // 5 KB
  const int tid  = threadIdx.x;
  const int lane = tid & 63;
  const int wid  = tid >> 6;
  const int wr = wid >> 1, wc = wid & 1;     // wave quadrant in 2x2 (32x32 each)
  const int fr = lane & 15;
  const int fk = (lane >> 4) << 3;
  const int m0 = blockIdx.y * 64, n0 = blockIdx.x * 64;

  f32x4 acc[2][2];
  const f32x4 zero = {0.f, 0.f, 0.f, 0.f};
#pragma unroll
  for (int i = 0; i < 2; ++i)
#pragma unroll
    for (int j = 0; j < 2; ++j) acc[i][j] = zero;

  // staging: thread t owns row t>>1 of combined [A(64) | W(64)], k-half (t&1)*16
  const int srow = tid >> 1;          // 0..127
  const int skh  = (tid & 1) << 4;    // 0 or 16
  const bool isA = srow < 64;
  const float* src;
  const float* src2 = nullptr;
  ushort* dst;
  if (isA) {
    int gr = m0 + srow; if (gr > M - 1) gr = M - 1;
    src = A + (size_t)gr * K + skh;
    if (X2) src2 = X2 + (size_t)gr * K + skh;
    dst = &As[srow * GP + skh];
  } else {
    src = Wm + (size_t)(n0 + srow - 64) * K + skh;
    dst = &Ws[(srow - 64) * GP + skh];
  }

  float4 pd[4];
#pragma unroll
  for (int i2 = 0; i2 < 4; ++i2) pd[i2] = *(const float4*)(src + i2 * 4);
  if (src2) {
#pragma unroll
    for (int i2 = 0; i2 < 4; ++i2) {
      const float4 u = *(const float4*)(src2 + i2 * 4);
      pd[i2].x += u.x; pd[i2].y += u.y; pd[i2].z += u.z; pd[i2].w += u.w;
    }
  }

  for (int k0 = 0; k0 < K; k0 += 32) {
    if (k0) __syncthreads();
    ushort tmp[16] __attribute__((aligned(16)));
#pragma unroll
    for (int i2 = 0; i2 < 4; ++i2) {
      tmp[i2*4+0] = f2bf(pd[i2].x); tmp[i2*4+1] = f2bf(pd[i2].y);
      tmp[i2*4+2] = f2bf(pd[i2].z); tmp[i2*4+3] = f2bf(pd[i2].w);
    }
    *(bf16x8*)(dst)     = *(const bf16x8*)&tmp[0];
    *(bf16x8*)(dst + 8) = *(const bf16x8*)&tmp[8];
    if (k0 + 32 < K) {
      const float* s = src + k0 + 32;
#pragma unroll
      for (int i2 = 0; i2 < 4; ++i2) pd[i2] = *(const float4*)(s + i2 * 4);
      if (src2) {
        const float* s2 = src2 + k0 + 32;
#pragma unroll
        for (int i2 = 0; i2 < 4; ++i2) {
          const float4 u = *(const float4*)(s2 + i2 * 4);
          pd[i2].x += u.x; pd[i2].y += u.y; pd[i2].z += u.z; pd[i2].w += u.w;
        }
      }
    }
    __syncthreads();

    bf16x8 af[2], bf[2];
#pragma unroll
    for (int i = 0; i < 2; ++i)
      af[i] = *(const bf16x8*)&As[(wr*32 + i*16 + fr)*GP + fk];
#pragma unroll
    for (int j = 0; j < 2; ++j)
      bf[j] = *(const bf16x8*)&Ws[(wc*32 + j*16 + fr)*GP + fk];
#pragma unroll
    for (int i = 0; i < 2; ++i)
#pragma unroll
      for (int j = 0; j < 2; ++j)
        acc[i][j] = __builtin_amdgcn_mfma_f32_16x16x32_bf16(af[i], bf[j], acc[i][j], 0, 0, 0);
  }

  const int gcolbase = n0 + wc * 32 + fr;
  float bias2[2];
#pragma unroll
  for (int j = 0; j < 2; ++j) bias2[j] = bias[gcolbase + j * 16];
#pragma unroll
  for (int i = 0; i < 2; ++i) {
    const int rb = m0 + wr * 32 + i * 16 + (lane >> 4) * 4;
#pragma unroll
    for (int r = 0; r < 4; ++r) {
      const int grow = rb + r;
      if (grow < M) {
#pragma unroll
        for (int j = 0; j < 2; ++j) {
          float v = acc[i][j][r] + bias2[j];
          if (relu) v = fmaxf(v, 0.f);
          if (outbf) ((ushort*)Y)[(size_t)grow * N + gcolbase + j * 16] = f2bf(v);
          else       Y[(size_t)grow * N + gcolbase + j * 16] = v;
        }
      }
    }
  }
}

// ---------------- self-attention: MFMA flash (swapped QK^T), bf16 ----------------
#define QB 64
#define KB 64
#define KP 40   // Ks / P pitch (ushort)
#define VP 72   // Vt pitch (ushort)
__global__ __launch_bounds__(256) void attn_mfma_kernel(
    const float* __restrict__ QK, const float* __restrict__ V,
    float* __restrict__ O)
{
  __shared__ ushort Ks[KB * KP];
  __shared__ ushort Vt[DH_ * VP];
  __shared__ ushort Pl[4][16 * KP];
  const int tid  = threadIdx.x;
  const int lane = tid & 63;
  const int w    = tid >> 6;
  const int bh = blockIdx.y;
  const int h  = bh & (HEADS_ - 1);
  const int b  = bh >> 3;
  const int q0 = blockIdx.x * QB;
  const int lq = lane & 15;
  const int lg = lane >> 4;
  const float scale = 0.17677669529663687f;
  const f32x4 zero4 = {0.f, 0.f, 0.f, 0.f};

  bf16x8 qf;
  {
    int qg = q0 + w * 16 + lq; if (qg > LQ_ - 1) qg = LQ_ - 1;
    const float* qp = QK + ((size_t)qg * B_ + b) * 512 + h * DH_ + lg * 8;
    const float4 a = *(const float4*)qp;
    const float4 c = *(const float4*)(qp + 4);
    ushort t[8] __attribute__((aligned(16)));
    t[0]=f2bf(a.x*scale); t[1]=f2bf(a.y*scale); t[2]=f2bf(a.z*scale); t[3]=f2bf(a.w*scale);
    t[4]=f2bf(c.x*scale); t[5]=f2bf(c.y*scale); t[6]=f2bf(c.z*scale); t[7]=f2bf(c.w*scale);
    qf = *(const bf16x8*)t;
  }

  float mrow = -1e30f, srow = 0.f;
  f32x4 oacc[2]; oacc[0] = zero4; oacc[1] = zero4;

  const int nkt = (LQ_ + KB - 1) / KB;   // 15
  for (int t = 0; t < nkt; ++t) {
    const int k0 = t * KB;
    const int klen = (LQ_ - k0) < KB ? (LQ_ - k0) : KB;
    if (t) __syncthreads();
    {
      const int kk  = tid >> 2;
      const int dh0 = (tid & 3) * 8;
      ushort kb[8] __attribute__((aligned(16)));
      ushort vb[8];
      if (kk < klen) {
        const size_t row = (size_t)(k0 + kk) * B_ + b;
        const float* kp = QK + row * 512 + 256 + h * DH_ + dh0;
        const float* vp = V  + row * 256 + h * DH_ + dh0;
        const float4 k1 = *(const float4*)kp;
        const float4 k2 = *(const float4*)(kp + 4);
        const float4 v1 = *(const float4*)vp;
        const float4 v2 = *(const float4*)(vp + 4);
        kb[0]=f2bf(k1.x); kb[1]=f2bf(k1.y); kb[2]=f2bf(k1.z); kb[3]=f2bf(k1.w);
        kb[4]=f2bf(k2.x); kb[5]=f2bf(k2.y); kb[6]=f2bf(k2.z); kb[7]=f2bf(k2.w);
        vb[0]=f2bf(v1.x); vb[1]=f2bf(v1.y); vb[2]=f2bf(v1.z); vb[3]=f2bf(v1.w);
        vb[4]=f2bf(v2.x); vb[5]=f2bf(v2.y); vb[6]=f2bf(v2.z); vb[7]=f2bf(v2.w);
      } else {
#pragma unroll
        for (int j = 0; j < 8; ++j) { kb[j] = 0; vb[j] = 0; }
      }
      *(bf16x8*)&Ks[kk * KP + dh0] = *(const bf16x8*)kb;
#pragma unroll
      for (int j = 0; j < 8; ++j) Vt[(dh0 + j) * VP + kk] = vb[j];
    }
    __syncthreads();

    f32x4 sc[4];
#pragma unroll
    for (int j = 0; j < 4; ++j) {
      const bf16x8 kf = *(const bf16x8*)&Ks[(j * 16 + lq) * KP + lg * 8];
      sc[j] = __builtin_amdgcn_mfma_f32_16x16x32_bf16(kf, qf, zero4, 0, 0, 0);
    }
    if (klen < KB) {
#pragma unroll
      for (int j = 0; j < 4; ++j)
#pragma unroll
        for (int r = 0; r < 4; ++r)
          if (j * 16 + lg * 4 + r >= klen) sc[j][r] = -1e30f;
    }
    float tmax = -1e30f;
#pragma unroll
    for (int j = 0; j < 4; ++j)
#pragma unroll
      for (int r = 0; r < 4; ++r) tmax = fmaxf(tmax, sc[j][r]);
    tmax = fmaxf(tmax, __shfl_xor(tmax, 16, 64));
    tmax = fmaxf(tmax, __shfl_xor(tmax, 32, 64));
    const float mnew = fmaxf(mrow, tmax);
    const float cfac = __expf(mrow - mnew);
    mrow = mnew;
    float tsum = 0.f;
#pragma unroll
    for (int j = 0; j < 4; ++j)
#pragma unroll
      for (int r = 0; r < 4; ++r) {
        const float p = __expf(sc[j][r] - mnew);
        sc[j][r] = p; tsum += p;
      }
    tsum += __shfl_xor(tsum, 16, 64);
    tsum += __shfl_xor(tsum, 32, 64);
    srow = srow * cfac + tsum;
#pragma unroll
    for (int j = 0; j < 4; ++j) {
      const uint lo = (uint)f2bf(sc[j][0]) | ((uint)f2bf(sc[j][1]) << 16);
      const uint hi = (uint)f2bf(sc[j][2]) | ((uint)f2bf(sc[j][3]) << 16);
      *(uint*)&Pl[w][lq * KP + j * 16 + lg * 4]     = lo;
      *(uint*)&Pl[w][lq * KP + j * 16 + lg * 4 + 2] = hi;
    }
    float crow[4];
#pragma unroll
    for (int r = 0; r < 4; ++r) crow[r] = __shfl(cfac, lg * 4 + r, 64);
#pragma unroll
    for (int nt = 0; nt < 2; ++nt)
#pragma unroll
      for (int r = 0; r < 4; ++r) oacc[nt][r] *= crow[r];
#pragma unroll
    for (int ks = 0; ks < 2; ++ks) {
      const bf16x8 pf = *(const bf16x8*)&Pl[w][lq * KP + ks * 32 + lg * 8];
#pragma unroll
      for (int nt = 0; nt < 2; ++nt) {
        const bf16x8 vf = *(const bf16x8*)&Vt[(nt * 16 + lq) * VP + ks * 32 + lg * 8];
        oacc[nt] = __builtin_amdgcn_mfma_f32_16x16x32_bf16(pf, vf, oacc[nt], 0, 0, 0);
      }
    }
  }
  float sinv[4];
#pragma unroll
  for (int r = 0; r < 4; ++r) {
    const float sr = __shfl(srow, lg * 4 + r, 64);
    sinv[r] = 1.f / sr;
  }
#pragma unroll
  for (int r = 0; r < 4; ++r) {
    const int qg = q0 + w * 16 + lg * 4 + r;
    if (qg < LQ_) {
      float* op = O + ((size_t)qg * B_ + b) * 256 + h * DH_;
      op[lq]      = oacc[0][r] * sinv[r];
      op[16 + lq] = oacc[1][r] * sinv[r];
    }
  }
}

// ---------------- residual + LayerNorm: Y = LN(X + R) * g + b ----------------
// 1 wave per row, float4 loads, pure-shuffle reduction; 4 rows/block.
__global__ __launch_bounds__(256) void ln_kernel(
    const float* __restrict__ X, const float* __restrict__ R,
    const float* __restrict__ g, const float* __restrict__ be,
    float* __restrict__ Y)
{
  const int row  = blockIdx.x * 4 + (threadIdx.x >> 6);
  const int lane = threadIdx.x & 63;
  const size_t base = (size_t)row * D_ + lane * 4;
  float4 v = *(const float4*)(X + base);
  const float4 rv = *(const float4*)(R + base);
  v.x += rv.x; v.y += rv.y; v.z += rv.z; v.w += rv.w;

  float sum = (v.x + v.y) + (v.z + v.w);
#pragma unroll
  for (int o = 32; o > 0; o >>= 1) sum += __shfl_xor(sum, o, 64);
  const float mean = sum * (1.f / D_);
  const float4 d = make_float4(v.x - mean, v.y - mean, v.z - mean, v.w - mean);
  float sq = (d.x * d.x + d.y * d.y) + (d.z * d.z + d.w * d.w);
#pragma unroll
  for (int o = 32; o > 0; o >>= 1) sq += __shfl_xor(sq, o, 64);
  const float rs = rsqrtf(sq * (1.f / D_) + 1e-5f);

  const float4 gv = *(const float4*)(g + lane * 4);
  const float4 bv = *(const float4*)(be + lane * 4);
  float4 o4;
  o4.x = d.x * rs * gv.x + bv.x;
  o4.y = d.y * rs * gv.y + bv.y;
  o4.z = d.z * rs * gv.z + bv.z;
  o4.w = d.w * rs * gv.w + bv.w;
  *(float4*)(Y + base) = o4;
}

// ---------------- MSDeformAttn sampling (bf16 value; 4 threads per (q,b,h)) ----------------
__global__ __launch_bounds__(256) void msdeform_kernel(
    const float* __restrict__ refp, const float* __restrict__ offb,
    const float* __restrict__ awb, const ushort* __restrict__ value,
    float* __restrict__ out)
{
  const int t  = blockIdx.x * 256 + threadIdx.x;   // < MQ*HEADS_*4
  const int dq = t & 3;            // dh quarter: 8 floats
  const int h  = (t >> 2) & 7;
  const int u  = t >> 5;           // b*LQ_ + q
  const int b  = u / LQ_;
  const int q  = u - b * LQ_;
  const int r  = q * B_ + b;

  float aw[LVLS_ * PTS_];
  const float* ap = awb + (size_t)r * 128 + h * 16;
  float m = -1e30f;
#pragma unroll
  for (int i = 0; i < 16; ++i) { aw[i] = ap[i]; m = fmaxf(m, aw[i]); }
  float s = 0.f;
#pragma unroll
  for (int i = 0; i < 16; ++i) { aw[i] = __expf(aw[i] - m); s += aw[i]; }
  const float inv = 1.f / s;
#pragma unroll
  for (int i = 0; i < 16; ++i) aw[i] *= inv;

  float o[8] = {};
  const int HH[4] = {100, 50, 25, 13};
  const int WW[4] = {100, 50, 25, 13};
  const int ST[4] = {0, 10000, 12500, 13125};
  const float* orow = offb + (size_t)r * 256 + h * (LVLS_ * PTS_ * 2);
  const int dh0 = h * DH_ + dq * 8;

  for (int l = 0; l < LVLS_; ++l) {
    const float4 rf = *(const float4*)(refp + (((size_t)q * B_ + b) * LVLS_ + l) * 4);
    const int W_ = WW[l], H_ = HH[l], s0 = ST[l];
    for (int p = 0; p < PTS_; ++p) {
      const float ox = orow[(l * PTS_ + p) * 2 + 0];
      const float oy = orow[(l * PTS_ + p) * 2 + 1];
      const float lx = rf.x + ox * 0.125f * rf.z;
      const float ly = rf.y + oy * 0.125f * rf.w;
      const float x = lx * W_ - 0.5f;
      const float y = ly * H_ - 0.5f;
      const float x0f = floorf(x), y0f = floorf(y);
      const float wx = x - x0f, wy = y - y0f;
      const int x0 = (int)x0f, y0 = (int)y0f;
      const float a = aw[l * PTS_ + p];
      const float cw[4] = {(1.f - wx) * (1.f - wy) * a, wx * (1.f - wy) * a,
                           (1.f - wx) * wy * a,         wx * wy * a};
      const int cx[4] = {x0, x0 + 1, x0, x0 + 1};
      const int cy[4] = {y0, y0, y0 + 1, y0 + 1};
#pragma unroll
      for (int c = 0; c < 4; ++c) {
        const int xi = cx[c], yi = cy[c];
        if (xi >= 0 && xi < W_ && yi >= 0 && yi < H_) {
          const ushort* vp = value + ((size_t)(s0 + yi * W_ + xi) * B_ + b) * 256 + dh0;
          const float w = cw[c];
          const bf16x8 vv = *(const bf16x8*)vp;   // 16 B
#pragma unroll
          for (int j = 0; j < 8; ++j)
            o[j] = fmaf(w, bf2f(((const ushort*)&vv)[j]), o[j]);
        }
      }
    }
  }
  float* op = out + (size_t)r * 256 + dh0;
  float4 x1; x1.x = o[0]; x1.y = o[1]; x1.z = o[2]; x1.w = o[3];
  float4 x2; x2.x = o[4]; x2.y = o[5]; x2.z = o[6]; x2.w = o[7];
  *(float4*)op = x1;
  *(float4*)(op + 4) = x2;
}

extern "C" void kernel_launch(void* const* d_in, const int* in_sizes, int n_in,
                              void* d_out, int out_size, void* d_ws, size_t ws_size,
                              hipStream_t stream) {
  const float* tgt       = (const float*)d_in[0];
  const float* pos       = (const float*)d_in[1];
  const float* refp      = (const float*)d_in[2];
  const float* memory    = (const float*)d_in[3];
  const float* in_proj_w = (const float*)d_in[6];
  const float* in_proj_b = (const float*)d_in[7];
  const float* sa_out_w  = (const float*)d_in[8];
  const float* sa_out_b  = (const float*)d_in[9];
  const float* off_w     = (const float*)d_in[10];
  const float* off_b     = (const float*)d_in[11];
  const float* aw_w      = (const float*)d_in[12];
  const float* aw_b      = (const float*)d_in[13];
  const float* val_w     = (const float*)d_in[14];
  const float* val_b     = (const float*)d_in[15];
  const float* ca_out_w  = (const float*)d_in[16];
  const float* ca_out_b  = (const float*)d_in[17];
  const float* lin1_w    = (const float*)d_in[18];
  const float* lin1_b    = (const float*)d_in[19];
  const float* lin2_w    = (const float*)d_in[20];
  const float* lin2_b    = (const float*)d_in[21];
  const float* n1g = (const float*)d_in[22];
  const float* n1b = (const float*)d_in[23];
  const float* n2g = (const float*)d_in[24];
  const float* n2b = (const float*)d_in[25];
  const float* n3g = (const float*)d_in[26];
  const float* n3b = (const float*)d_in[27];

  float* ws = (float*)d_ws;
  float* QK    = ws;                               // MQ*512
  float* Vb    = QK   + (size_t)MQ * 512;          // MQ*256
  float* Cb    = Vb   + (size_t)MQ * 256;          // MQ*256
  float* Db    = Cb   + (size_t)MQ * 256;          // MQ*256
  float* tgt1  = Db   + (size_t)MQ * 256;          // MQ*256
  float* tgt2  = tgt1 + (size_t)MQ * 256;          // MQ*256
  float* big   = tgt2 + (size_t)MQ * 256;          // max(MV*128, MQ*1024) floats
  ushort* value = (ushort*)big;                    // MV*256 bf16
  float* mid   = big;   // FFN mid aliases value region (disjoint lifetimes)

  const dim3 blk(256);
  const int gy_q = (MQ + 63) / 64;        // 225
  const int gy_v128 = (MV + 127) / 128;   // 1662
  const int qtiles = (LQ_ + QB - 1) / QB; // 15

  // 1) Q,K projections (input tgt+pos), N=512 — bf16 MFMA 64-tile
  gemm_bf16_64<<<dim3(8, gy_q), blk, 0, stream>>>(tgt, pos, in_proj_w, in_proj_b, QK, MQ, 512, D_, 0, 0);
  // 2) V projection (input tgt), N=256 — bf16 MFMA 64-tile
  gemm_bf16_64<<<dim3(4, gy_q), blk, 0, stream>>>(tgt, nullptr, in_proj_w + 512 * D_, in_proj_b + 512, Vb, MQ, 256, D_, 0, 0);
  // 3) self-attention — bf16 MFMA flash
  attn_mfma_kernel<<<dim3(qtiles, B_ * HEADS_), blk, 0, stream>>>(QK, Vb, Cb);
  // 4) SA out proj — bf16 MFMA 64-tile
  gemm_bf16_64<<<dim3(4, gy_q), blk, 0, stream>>>(Cb, nullptr, sa_out_w, sa_out_b, Db, MQ, 256, D_, 0, 0);
  // 5) tgt1 = LN(tgt + sa; norm2)
  ln_kernel<<<MQ / 4, blk, 0, stream>>>(tgt, Db, n2g, n2b, tgt1);
  // 6) value projection over memory — bf16 MFMA 128-tile / 8 waves / BK=32 (R10 best), bf16 out
  gemm_bf16_512<<<dim3(2, gy_v128), dim3(512), 0, stream>>>(memory, val_w, val_b, (float*)value, MV, 256, D_, 0, 1);
  // 7) sampling offsets (input tgt1+pos) — bf16 64-tile
  gemm_bf16_64<<<dim3(4, gy_q), blk, 0, stream>>>(tgt1, pos, off_w, off_b, QK, MQ, 256, D_, 0, 0);
  // 8) attention-weight logits — bf16 64-tile
  gemm_bf16_64<<<dim3(2, gy_q), blk, 0, stream>>>(tgt1, pos, aw_w, aw_b, Vb, MQ, 128, D_, 0, 0);
  // 9) deformable sampling -> Cb  (bf16 value gather)
  msdeform_kernel<<<(MQ * HEADS_ * 4 + 255) / 256, blk, 0, stream>>>(refp, QK, Vb, value, Cb);
  // 10) CA out proj — bf16 MFMA 64-tile
  gemm_bf16_64<<<dim3(4, gy_q), blk, 0, stream>>>(Cb, nullptr, ca_out_w, ca_out_b, Db, MQ, 256, D_, 0, 0);
  // 11) tgt2 = LN(tgt1 + ca; norm1)
  ln_kernel<<<MQ / 4, blk, 0, stream>>>(tgt1, Db, n1g, n1b, tgt2);
  // 12) FFN lin1 + relu -> mid — bf16 MFMA 64-tile
  gemm_bf16_64<<<dim3(16, gy_q), blk, 0, stream>>>(tgt2, nullptr, lin1_w, lin1_b, mid, MQ, DFF_, D_, 1, 0);
  // 13) FFN lin2 -> Db — bf16 MFMA 64-tile (K=1024)
  gemm_bf16_64<<<dim3(4, gy_q), blk, 0, stream>>>(mid, nullptr, lin2_w, lin2_b, Db, MQ, 256, DFF_, 0, 0);
  // 14) out = LN(tgt2 + ffn; norm3)
  ln_kernel<<<MQ / 4, blk, 0, stream>>>(tgt2, Db, n3g, n3b, (float*)d_out);
}

// Round 14
// 522.799 us; speedup vs baseline: 1.1166x; 1.0106x over previous
//
#include <hip/hip_runtime.h>
#include <hip/hip_bf16.h>
#include <math.h>

#define D_ 256
#define HEADS_ 8
#define DH_ 32
#define LVLS_ 4
#define PTS_ 4
#define DFF_ 1024
#define LQ_ 900
#define B_ 16
#define S_ 13294
#define MQ (LQ_*B_)      // 14400
#define MV (S_*B_)       // 212704

typedef __attribute__((ext_vector_type(4))) float f32x4;
typedef __attribute__((ext_vector_type(8))) short bf16x8;

static __device__ inline ushort f2bf(float f) {
  __hip_bfloat16 h = __float2bfloat16(f);   // RNE
  union { __hip_bfloat16 h; ushort u; } c; c.h = h;
  return c.u;
}
static __device__ inline float bf2f(ushort u) {
  union { float f; uint u; } c; c.u = (uint)u << 16; return c.f;
}

#define GP 40   // LDS pitch in ushorts (80 B rows)

// ---------------- bf16-MFMA GEMM, 128x128 tile, 8 waves, BK=32 ----------------
// R10 variant — best measured on the value projection (136 us).
__global__ __launch_bounds__(512) void gemm_bf16_512(
    const float* __restrict__ A, const float* __restrict__ Wm,
    const float* __restrict__ bias, float* __restrict__ Y,
    int M, int N, int K, int relu, int outbf)
{
  __shared__ ushort As[128 * GP];   // 10 KB
  __shared__ ushort Ws[128 * GP];   // 10 KB
  const int tid  = threadIdx.x;
  const int lane = tid & 63;
  const int wid  = tid >> 6;          // 0..7
  const int wr   = wid >> 1;          // 0..3: 32-row band
  const int wc   = wid & 1;           // 0..1: 64-col half
  const int fr = lane & 15;
  const int fk = (lane >> 4) << 3;
  const int m0 = blockIdx.y * 128, n0 = blockIdx.x * 128;

  f32x4 acc[2][4];
  const f32x4 zero = {0.f, 0.f, 0.f, 0.f};
#pragma unroll
  for (int i = 0; i < 2; ++i)
#pragma unroll
    for (int j = 0; j < 4; ++j) acc[i][j] = zero;

  const int srow = tid >> 2;
  const int skh  = (tid & 3) << 3;
  int agr = m0 + srow; if (agr > M - 1) agr = M - 1;
  const float* apb = A  + (size_t)agr * K + skh;
  const float* wpb = Wm + (size_t)(n0 + srow) * K + skh;

  float4 pa[2], pw[2];
  pa[0] = *(const float4*)(apb);     pa[1] = *(const float4*)(apb + 4);
  pw[0] = *(const float4*)(wpb);     pw[1] = *(const float4*)(wpb + 4);

  for (int k0 = 0; k0 < K; k0 += 32) {
    if (k0) __syncthreads();
    ushort tmp[8] __attribute__((aligned(16)));
    tmp[0]=f2bf(pa[0].x); tmp[1]=f2bf(pa[0].y); tmp[2]=f2bf(pa[0].z); tmp[3]=f2bf(pa[0].w);
    tmp[4]=f2bf(pa[1].x); tmp[5]=f2bf(pa[1].y); tmp[6]=f2bf(pa[1].z); tmp[7]=f2bf(pa[1].w);
    *(bf16x8*)&As[srow*GP + skh] = *(const bf16x8*)tmp;
    tmp[0]=f2bf(pw[0].x); tmp[1]=f2bf(pw[0].y); tmp[2]=f2bf(pw[0].z); tmp[3]=f2bf(pw[0].w);
    tmp[4]=f2bf(pw[1].x); tmp[5]=f2bf(pw[1].y); tmp[6]=f2bf(pw[1].z); tmp[7]=f2bf(pw[1].w);
    *(bf16x8*)&Ws[srow*GP + skh] = *(const bf16x8*)tmp;
    if (k0 + 32 < K) {
      const float* ap = apb + k0 + 32;
      const float* wp = wpb + k0 + 32;
      pa[0] = *(const float4*)(ap);  pa[1] = *(const float4*)(ap + 4);
      pw[0] = *(const float4*)(wp);  pw[1] = *(const float4*)(wp + 4);
    }
    __syncthreads();

    bf16x8 ar[2], br[4];
#pragma unroll
    for (int i = 0; i < 2; ++i)
      ar[i] = *(const bf16x8*)&As[(wr*32 + i*16 + fr)*GP + fk];
#pragma unroll
    for (int j = 0; j < 4; ++j)
      br[j] = *(const bf16x8*)&Ws[(wc*64 + j*16 + fr)*GP + fk];
#pragma unroll
    for (int i = 0; i < 2; ++i)
#pragma unroll
      for (int j = 0; j < 4; ++j)
        acc[i][j] = __builtin_amdgcn_mfma_f32_16x16x32_bf16(ar[i], br[j], acc[i][j], 0, 0, 0);
  }

  const int gcolbase = n0 + wc * 64 + fr;
  float bias4[4];
#pragma unroll
  for (int j = 0; j < 4; ++j) bias4[j] = bias[gcolbase + j * 16];
#pragma unroll
  for (int i = 0; i < 2; ++i) {
    const int rb = m0 + wr * 32 + i * 16 + (lane >> 4) * 4;
#pragma unroll
    for (int r = 0; r < 4; ++r) {
      const int grow = rb + r;
      if (grow < M) {
#pragma unroll
        for (int j = 0; j < 4; ++j) {
          float v = acc[i][j][r] + bias4[j];
          if (relu) v = fmaxf(v, 0.f);
          if (outbf) ((ushort*)Y)[(size_t)grow * N + gcolbase + j * 16] = f2bf(v);
          else       Y[(size_t)grow * N + gcolbase + j * 16] = v;
        }
      }
    }
  }
}

// ---------------- bf16-MFMA GEMM, 64x64 tile ----------------
__global__ __launch_bounds__(256) void gemm_bf16_64(
    const float* __restrict__ A, const float* __restrict__ X2,
    const float* __restrict__ Wm, const float* __restrict__ bias,
    float* __restrict__ Y, int M, int N, int K, int relu, int outbf)
{
  __shared__ ushort As[64 * GP];   // 5 KB
  __shared__ ushort Ws[64 * GP];   // 5 KB
  const int tid  = threadIdx.x;
  const int lane = tid & 63;
  const int wid  = tid >> 6;
  const int wr = wid >> 1, wc = wid & 1;
  const int fr = lane & 15;
  const int fk = (lane >> 4) << 3;
  const int m0 = blockIdx.y * 64, n0 = blockIdx.x * 64;

  f32x4 acc[2][2];
  const f32x4 zero = {0.f, 0.f, 0.f, 0.f};
#pragma unroll
  for (int i = 0; i < 2; ++i)
#pragma unroll
    for (int j = 0; j < 2; ++j) acc[i][j] = zero;

  const int srow = tid >> 1;          // 0..127
  const int skh  = (tid & 1) << 4;    // 0 or 16
  const bool isA = srow < 64;
  const float* src;
  const float* src2 = nullptr;
  ushort* dst;
  if (isA) {
    int gr = m0 + srow; if (gr > M - 1) gr = M - 1;
    src = A + (size_t)gr * K + skh;
    if (X2) src2 = X2 + (size_t)gr * K + skh;
    dst = &As[srow * GP + skh];
  } else {
    src = Wm + (size_t)(n0 + srow - 64) * K + skh;
    dst = &Ws[(srow - 64) * GP + skh];
  }

  float4 pd[4];
#pragma unroll
  for (int i2 = 0; i2 < 4; ++i2) pd[i2] = *(const float4*)(src + i2 * 4);
  if (src2) {
#pragma unroll
    for (int i2 = 0; i2 < 4; ++i2) {
      const float4 u = *(const float4*)(src2 + i2 * 4);
      pd[i2].x += u.x; pd[i2].y += u.y; pd[i2].z += u.z; pd[i2].w += u.w;
    }
  }

  for (int k0 = 0; k0 < K; k0 += 32) {
    if (k0) __syncthreads();
    ushort tmp[16] __attribute__((aligned(16)));
#pragma unroll
    for (int i2 = 0; i2 < 4; ++i2) {
      tmp[i2*4+0] = f2bf(pd[i2].x); tmp[i2*4+1] = f2bf(pd[i2].y);
      tmp[i2*4+2] = f2bf(pd[i2].z); tmp[i2*4+3] = f2bf(pd[i2].w);
    }
    *(bf16x8*)(dst)     = *(const bf16x8*)&tmp[0];
    *(bf16x8*)(dst + 8) = *(const bf16x8*)&tmp[8];
    if (k0 + 32 < K) {
      const float* s = src + k0 + 32;
#pragma unroll
      for (int i2 = 0; i2 < 4; ++i2) pd[i2] = *(const float4*)(s + i2 * 4);
      if (src2) {
        const float* s2 = src2 + k0 + 32;
#pragma unroll
        for (int i2 = 0; i2 < 4; ++i2) {
          const float4 u = *(const float4*)(s2 + i2 * 4);
          pd[i2].x += u.x; pd[i2].y += u.y; pd[i2].z += u.z; pd[i2].w += u.w;
        }
      }
    }
    __syncthreads();

    bf16x8 af[2], bf[2];
#pragma unroll
    for (int i = 0; i < 2; ++i)
      af[i] = *(const bf16x8*)&As[(wr*32 + i*16 + fr)*GP + fk];
#pragma unroll
    for (int j = 0; j < 2; ++j)
      bf[j] = *(const bf16x8*)&Ws[(wc*32 + j*16 + fr)*GP + fk];
#pragma unroll
    for (int i = 0; i < 2; ++i)
#pragma unroll
      for (int j = 0; j < 2; ++j)
        acc[i][j] = __builtin_amdgcn_mfma_f32_16x16x32_bf16(af[i], bf[j], acc[i][j], 0, 0, 0);
  }

  const int gcolbase = n0 + wc * 32 + fr;
  float bias2[2];
#pragma unroll
  for (int j = 0; j < 2; ++j) bias2[j] = bias[gcolbase + j * 16];
#pragma unroll
  for (int i = 0; i < 2; ++i) {
    const int rb = m0 + wr * 32 + i * 16 + (lane >> 4) * 4;
#pragma unroll
    for (int r = 0; r < 4; ++r) {
      const int grow = rb + r;
      if (grow < M) {
#pragma unroll
        for (int j = 0; j < 2; ++j) {
          float v = acc[i][j][r] + bias2[j];
          if (relu) v = fmaxf(v, 0.f);
          if (outbf) ((ushort*)Y)[(size_t)grow * N + gcolbase + j * 16] = f2bf(v);
          else       Y[(size_t)grow * N + gcolbase + j * 16] = v;
        }
      }
    }
  }
}

// ---------------- self-attention: MFMA flash (swapped QK^T), bf16 ----------------
// QB=128: 4 waves x 32 q-rows each -> 16 MFMAs per staged K/V tile per wave
// (2x amortization of staging/barriers vs QB=64). V staged via packed u32 writes.
#define QB 128
#define KB 64
#define KP 40   // Ks / P pitch (ushort)
#define VP 72   // Vt pitch (ushort)
__global__ __launch_bounds__(256) void attn_mfma_kernel(
    const float* __restrict__ QK, const float* __restrict__ V,
    float* __restrict__ O)
{
  __shared__ ushort Ks[KB * KP];       // 5120 B
  __shared__ ushort Vt[DH_ * VP];      // 4608 B
  __shared__ ushort Pl[4][32 * KP];    // 10240 B
  const int tid  = threadIdx.x;
  const int lane = tid & 63;
  const int w    = tid >> 6;
  const int bh = blockIdx.y;
  const int h  = bh & (HEADS_ - 1);
  const int b  = bh >> 3;
  const int q0 = blockIdx.x * QB;
  const int lq = lane & 15;
  const int lg = lane >> 4;
  const float scale = 0.17677669529663687f;
  const f32x4 zero4 = {0.f, 0.f, 0.f, 0.f};

  // Q fragments: s=0,1 -> rows q0 + w*32 + s*16 + lq, dh-slice lg*8, pre-scaled
  bf16x8 qf[2];
#pragma unroll
  for (int s = 0; s < 2; ++s) {
    int qg = q0 + w * 32 + s * 16 + lq; if (qg > LQ_ - 1) qg = LQ_ - 1;
    const float* qp = QK + ((size_t)qg * B_ + b) * 512 + h * DH_ + lg * 8;
    const float4 a = *(const float4*)qp;
    const float4 c = *(const float4*)(qp + 4);
    ushort t[8] __attribute__((aligned(16)));
    t[0]=f2bf(a.x*scale); t[1]=f2bf(a.y*scale); t[2]=f2bf(a.z*scale); t[3]=f2bf(a.w*scale);
    t[4]=f2bf(c.x*scale); t[5]=f2bf(c.y*scale); t[6]=f2bf(c.z*scale); t[7]=f2bf(c.w*scale);
    qf[s] = *(const bf16x8*)t;
  }

  float mrow[2] = {-1e30f, -1e30f}, srow[2] = {0.f, 0.f};
  f32x4 oacc[2][2];
  oacc[0][0] = zero4; oacc[0][1] = zero4; oacc[1][0] = zero4; oacc[1][1] = zero4;

  const int nkt = (LQ_ + KB - 1) / KB;   // 15
  for (int t = 0; t < nkt; ++t) {
    const int k0 = t * KB;
    const int klen = (LQ_ - k0) < KB ? (LQ_ - k0) : KB;
    if (t) __syncthreads();
    // ---- stage K: thread row tid>>2, dh0 = (tid&3)*8, b128 write ----
    {
      const int kk  = tid >> 2;
      const int dh0 = (tid & 3) * 8;
      ushort kb[8] __attribute__((aligned(16)));
      if (kk < klen) {
        const float* kp = QK + ((size_t)(k0 + kk) * B_ + b) * 512 + 256 + h * DH_ + dh0;
        const float4 k1 = *(const float4*)kp;
        const float4 k2 = *(const float4*)(kp + 4);
        kb[0]=f2bf(k1.x); kb[1]=f2bf(k1.y); kb[2]=f2bf(k1.z); kb[3]=f2bf(k1.w);
        kb[4]=f2bf(k2.x); kb[5]=f2bf(k2.y); kb[6]=f2bf(k2.z); kb[7]=f2bf(k2.w);
      } else {
#pragma unroll
        for (int j = 0; j < 8; ++j) kb[j] = 0;
      }
      *(bf16x8*)&Ks[kk * KP + dh0] = *(const bf16x8*)kb;
    }
    // ---- stage V transposed: thread keys kk2,kk2+1 x 4 dh; packed u32 writes ----
    {
      const int kk2  = (tid >> 3) << 1;     // 0,2,..,62
      const int dh0v = (tid & 7) * 4;       // 0,4,..,28
      float v0[4] = {0.f, 0.f, 0.f, 0.f};
      float v1[4] = {0.f, 0.f, 0.f, 0.f};
      if (kk2 < klen) {
        const float4 x = *(const float4*)(V + ((size_t)(k0 + kk2) * B_ + b) * 256 + h * DH_ + dh0v);
        v0[0] = x.x; v0[1] = x.y; v0[2] = x.z; v0[3] = x.w;
      }
      if (kk2 + 1 < klen) {
        const float4 x = *(const float4*)(V + ((size_t)(k0 + kk2 + 1) * B_ + b) * 256 + h * DH_ + dh0v);
        v1[0] = x.x; v1[1] = x.y; v1[2] = x.z; v1[3] = x.w;
      }
#pragma unroll
      for (int j = 0; j < 4; ++j) {
        const uint pk = (uint)f2bf(v0[j]) | ((uint)f2bf(v1[j]) << 16);
        *(uint*)&Vt[(dh0v + j) * VP + kk2] = pk;
      }
    }
    __syncthreads();

    float cfac[2];
#pragma unroll
    for (int s = 0; s < 2; ++s) {
      // ---- S^T = K . Q^T: 4 MFMAs; lane holds 16 scores for query s*16+lq ----
      f32x4 sc[4];
#pragma unroll
      for (int j = 0; j < 4; ++j) {
        const bf16x8 kf = *(const bf16x8*)&Ks[(j * 16 + lq) * KP + lg * 8];
        sc[j] = __builtin_amdgcn_mfma_f32_16x16x32_bf16(kf, qf[s], zero4, 0, 0, 0);
      }
      if (klen < KB) {
#pragma unroll
        for (int j = 0; j < 4; ++j)
#pragma unroll
          for (int r = 0; r < 4; ++r)
            if (j * 16 + lg * 4 + r >= klen) sc[j][r] = -1e30f;
      }
      float tmax = -1e30f;
#pragma unroll
      for (int j = 0; j < 4; ++j)
#pragma unroll
        for (int r = 0; r < 4; ++r) tmax = fmaxf(tmax, sc[j][r]);
      tmax = fmaxf(tmax, __shfl_xor(tmax, 16, 64));
      tmax = fmaxf(tmax, __shfl_xor(tmax, 32, 64));
      const float mnew = fmaxf(mrow[s], tmax);
      cfac[s] = __expf(mrow[s] - mnew);
      mrow[s] = mnew;
      float tsum = 0.f;
#pragma unroll
      for (int j = 0; j < 4; ++j)
#pragma unroll
        for (int r = 0; r < 4; ++r) {
          const float p = __expf(sc[j][r] - mnew);
          sc[j][r] = p; tsum += p;
        }
      tsum += __shfl_xor(tsum, 16, 64);
      tsum += __shfl_xor(tsum, 32, 64);
      srow[s] = srow[s] * cfac[s] + tsum;
      // ---- pack P -> Pl (rows = s*16+lq, cols = key) ----
#pragma unroll
      for (int j = 0; j < 4; ++j) {
        const uint lo = (uint)f2bf(sc[j][0]) | ((uint)f2bf(sc[j][1]) << 16);
        const uint hi = (uint)f2bf(sc[j][2]) | ((uint)f2bf(sc[j][3]) << 16);
        *(uint*)&Pl[w][(s * 16 + lq) * KP + j * 16 + lg * 4]     = lo;
        *(uint*)&Pl[w][(s * 16 + lq) * KP + j * 16 + lg * 4 + 2] = hi;
      }
    }
    // ---- rescale O and accumulate PV per s ----
#pragma unroll
    for (int s = 0; s < 2; ++s) {
      float crow[4];
#pragma unroll
      for (int r = 0; r < 4; ++r) crow[r] = __shfl(cfac[s], lg * 4 + r, 64);
#pragma unroll
      for (int nt = 0; nt < 2; ++nt)
#pragma unroll
        for (int r = 0; r < 4; ++r) oacc[s][nt][r] *= crow[r];
#pragma unroll
      for (int ks = 0; ks < 2; ++ks) {
        const bf16x8 pf = *(const bf16x8*)&Pl[w][(s * 16 + lq) * KP + ks * 32 + lg * 8];
#pragma unroll
        for (int nt = 0; nt < 2; ++nt) {
          const bf16x8 vf = *(const bf16x8*)&Vt[(nt * 16 + lq) * VP + ks * 32 + lg * 8];
          oacc[s][nt] = __builtin_amdgcn_mfma_f32_16x16x32_bf16(pf, vf, oacc[s][nt], 0, 0, 0);
        }
      }
    }
  }
  // ---- epilogue ----
#pragma unroll
  for (int s = 0; s < 2; ++s) {
    float sinv[4];
#pragma unroll
    for (int r = 0; r < 4; ++r) {
      const float sr = __shfl(srow[s], lg * 4 + r, 64);
      sinv[r] = 1.f / sr;
    }
#pragma unroll
    for (int r = 0; r < 4; ++r) {
      const int qg = q0 + w * 32 + s * 16 + lg * 4 + r;
      if (qg < LQ_) {
        float* op = O + ((size_t)qg * B_ + b) * 256 + h * DH_;
        op[lq]      = oacc[s][0][r] * sinv[r];
        op[16 + lq] = oacc[s][1][r] * sinv[r];
      }
    }
  }
}

// ---------------- residual + LayerNorm: Y = LN(X + R) * g + b ----------------
// 1 wave per row, float4 loads, pure-shuffle reduction; 4 rows/block.
__global__ __launch_bounds__(256) void ln_kernel(
    const float* __restrict__ X, const float* __restrict__ R,
    const float* __restrict__ g, const float* __restrict__ be,
    float* __restrict__ Y)
{
  const int row  = blockIdx.x * 4 + (threadIdx.x >> 6);
  const int lane = threadIdx.x & 63;
  const size_t base = (size_t)row * D_ + lane * 4;
  float4 v = *(const float4*)(X + base);
  const float4 rv = *(const float4*)(R + base);
  v.x += rv.x; v.y += rv.y; v.z += rv.z; v.w += rv.w;

  float sum = (v.x + v.y) + (v.z + v.w);
#pragma unroll
  for (int o = 32; o > 0; o >>= 1) sum += __shfl_xor(sum, o, 64);
  const float mean = sum * (1.f / D_);
  const float4 d = make_float4(v.x - mean, v.y - mean, v.z - mean, v.w - mean);
  float sq = (d.x * d.x + d.y * d.y) + (d.z * d.z + d.w * d.w);
#pragma unroll
  for (int o = 32; o > 0; o >>= 1) sq += __shfl_xor(sq, o, 64);
  const float rs = rsqrtf(sq * (1.f / D_) + 1e-5f);

  const float4 gv = *(const float4*)(g + lane * 4);
  const float4 bv = *(const float4*)(be + lane * 4);
  float4 o4;
  o4.x = d.x * rs * gv.x + bv.x;
  o4.y = d.y * rs * gv.y + bv.y;
  o4.z = d.z * rs * gv.z + bv.z;
  o4.w = d.w * rs * gv.w + bv.w;
  *(float4*)(Y + base) = o4;
}

// ---------------- MSDeformAttn sampling (bf16 value; 4 threads per (q,b,h)) ----------------
__global__ __launch_bounds__(256) void msdeform_kernel(
    const float* __restrict__ refp, const float* __restrict__ offb,
    const float* __restrict__ awb, const ushort* __restrict__ value,
    float* __restrict__ out)
{
  const int t  = blockIdx.x * 256 + threadIdx.x;   // < MQ*HEADS_*4
  const int dq = t & 3;            // dh quarter: 8 floats
  const int h  = (t >> 2) & 7;
  const int u  = t >> 5;           // b*LQ_ + q
  const int b  = u / LQ_;
  const int q  = u - b * LQ_;
  const int r  = q * B_ + b;

  float aw[LVLS_ * PTS_];
  const float* ap = awb + (size_t)r * 128 + h * 16;
  float m = -1e30f;
#pragma unroll
  for (int i = 0; i < 16; ++i) { aw[i] = ap[i]; m = fmaxf(m, aw[i]); }
  float s = 0.f;
#pragma unroll
  for (int i = 0; i < 16; ++i) { aw[i] = __expf(aw[i] - m); s += aw[i]; }
  const float inv = 1.f / s;
#pragma unroll
  for (int i = 0; i < 16; ++i) aw[i] *= inv;

  float o[8] = {};
  const int HH[4] = {100, 50, 25, 13};
  const int WW[4] = {100, 50, 25, 13};
  const int ST[4] = {0, 10000, 12500, 13125};
  const float* orow = offb + (size_t)r * 256 + h * (LVLS_ * PTS_ * 2);
  const int dh0 = h * DH_ + dq * 8;

  for (int l = 0; l < LVLS_; ++l) {
    const float4 rf = *(const float4*)(refp + (((size_t)q * B_ + b) * LVLS_ + l) * 4);
    const int W_ = WW[l], H_ = HH[l], s0 = ST[l];
    for (int p = 0; p < PTS_; ++p) {
      const float ox = orow[(l * PTS_ + p) * 2 + 0];
      const float oy = orow[(l * PTS_ + p) * 2 + 1];
      const float lx = rf.x + ox * 0.125f * rf.z;
      const float ly = rf.y + oy * 0.125f * rf.w;
      const float x = lx * W_ - 0.5f;
      const float y = ly * H_ - 0.5f;
      const float x0f = floorf(x), y0f = floorf(y);
      const float wx = x - x0f, wy = y - y0f;
      const int x0 = (int)x0f, y0 = (int)y0f;
      const float a = aw[l * PTS_ + p];
      const float cw[4] = {(1.f - wx) * (1.f - wy) * a, wx * (1.f - wy) * a,
                           (1.f - wx) * wy * a,         wx * wy * a};
      const int cx[4] = {x0, x0 + 1, x0, x0 + 1};
      const int cy[4] = {y0, y0, y0 + 1, y0 + 1};
#pragma unroll
      for (int c = 0; c < 4; ++c) {
        const int xi = cx[c], yi = cy[c];
        if (xi >= 0 && xi < W_ && yi >= 0 && yi < H_) {
          const ushort* vp = value + ((size_t)(s0 + yi * W_ + xi) * B_ + b) * 256 + dh0;
          const float w = cw[c];
          const bf16x8 vv = *(const bf16x8*)vp;   // 16 B
#pragma unroll
          for (int j = 0; j < 8; ++j)
            o[j] = fmaf(w, bf2f(((const ushort*)&vv)[j]), o[j]);
        }
      }
    }
  }
  float* op = out + (size_t)r * 256 + dh0;
  float4 x1; x1.x = o[0]; x1.y = o[1]; x1.z = o[2]; x1.w = o[3];
  float4 x2; x2.x = o[4]; x2.y = o[5]; x2.z = o[6]; x2.w = o[7];
  *(float4*)op = x1;
  *(float4*)(op + 4) = x2;
}

extern "C" void kernel_launch(void* const* d_in, const int* in_sizes, int n_in,
                              void* d_out, int out_size, void* d_ws, size_t ws_size,
                              hipStream_t stream) {
  const float* tgt       = (const float*)d_in[0];
  const float* pos       = (const float*)d_in[1];
  const float* refp      = (const float*)d_in[2];
  const float* memory    = (const float*)d_in[3];
  const float* in_proj_w = (const float*)d_in[6];
  const float* in_proj_b = (const float*)d_in[7];
  const float* sa_out_w  = (const float*)d_in[8];
  const float* sa_out_b  = (const float*)d_in[9];
  const float* off_w     = (const float*)d_in[10];
  const float* off_b     = (const float*)d_in[11];
  const float* aw_w      = (const float*)d_in[12];
  const float* aw_b      = (const float*)d_in[13];
  const float* val_w     = (const float*)d_in[14];
  const float* val_b     = (const float*)d_in[15];
  const float* ca_out_w  = (const float*)d_in[16];
  const float* ca_out_b  = (const float*)d_in[17];
  const float* lin1_w    = (const float*)d_in[18];
  const float* lin1_b    = (const float*)d_in[19];
  const float* lin2_w    = (const float*)d_in[20];
  const float* lin2_b    = (const float*)d_in[21];
  const float* n1g = (const float*)d_in[22];
  const float* n1b = (const float*)d_in[23];
  const float* n2g = (const float*)d_in[24];
  const float* n2b = (const float*)d_in[25];
  const float* n3g = (const float*)d_in[26];
  const float* n3b = (const float*)d_in[27];

  float* ws = (float*)d_ws;
  float* QK    = ws;                               // MQ*512
  float* Vb    = QK   + (size_t)MQ * 512;          // MQ*256
  float* Cb    = Vb   + (size_t)MQ * 256;          // MQ*256
  float* Db    = Cb   + (size_t)MQ * 256;          // MQ*256
  float* tgt1  = Db   + (size_t)MQ * 256;          // MQ*256
  float* tgt2  = tgt1 + (size_t)MQ * 256;          // MQ*256
  float* big   = tgt2 + (size_t)MQ * 256;          // max(MV*128, MQ*1024) floats
  ushort* value = (ushort*)big;                    // MV*256 bf16
  float* mid   = big;   // FFN mid aliases value region (disjoint lifetimes)

  const dim3 blk(256);
  const int gy_q = (MQ + 63) / 64;        // 225
  const int gy_v128 = (MV + 127) / 128;   // 1662
  const int qtiles = (LQ_ + QB - 1) / QB; // 8

  // 1) Q,K projections (input tgt+pos), N=512 — bf16 MFMA 64-tile
  gemm_bf16_64<<<dim3(8, gy_q), blk, 0, stream>>>(tgt, pos, in_proj_w, in_proj_b, QK, MQ, 512, D_, 0, 0);
  // 2) V projection (input tgt), N=256 — bf16 MFMA 64-tile
  gemm_bf16_64<<<dim3(4, gy_q), blk, 0, stream>>>(tgt, nullptr, in_proj_w + 512 * D_, in_proj_b + 512, Vb, MQ, 256, D_, 0, 0);
  // 3) self-attention — bf16 MFMA flash, QB=128
  attn_mfma_kernel<<<dim3(qtiles, B_ * HEADS_), blk, 0, stream>>>(QK, Vb, Cb);
  // 4) SA out proj — bf16 MFMA 64-tile
  gemm_bf16_64<<<dim3(4, gy_q), blk, 0, stream>>>(Cb, nullptr, sa_out_w, sa_out_b, Db, MQ, 256, D_, 0, 0);
  // 5) tgt1 = LN(tgt + sa; norm2)
  ln_kernel<<<MQ / 4, blk, 0, stream>>>(tgt, Db, n2g, n2b, tgt1);
  // 6) value projection over memory — bf16 MFMA 128-tile / 8 waves / BK=32, bf16 out
  gemm_bf16_512<<<dim3(2, gy_v128), dim3(512), 0, stream>>>(memory, val_w, val_b, (float*)value, MV, 256, D_, 0, 1);
  // 7) sampling offsets (input tgt1+pos) — bf16 64-tile
  gemm_bf16_64<<<dim3(4, gy_q), blk, 0, stream>>>(tgt1, pos, off_w, off_b, QK, MQ, 256, D_, 0, 0);
  // 8) attention-weight logits — bf16 64-tile
  gemm_bf16_64<<<dim3(2, gy_q), blk, 0, stream>>>(tgt1, pos, aw_w, aw_b, Vb, MQ, 128, D_, 0, 0);
  // 9) deformable sampling -> Cb  (bf16 value gather)
  msdeform_kernel<<<(MQ * HEADS_ * 4 + 255) / 256, blk, 0, stream>>>(refp, QK, Vb, value, Cb);
  // 10) CA out proj — bf16 MFMA 64-tile
  gemm_bf16_64<<<dim3(4, gy_q), blk, 0, stream>>>(Cb, nullptr, ca_out_w, ca_out_b, Db, MQ, 256, D_, 0, 0);
  // 11) tgt2 = LN(tgt1 + ca; norm1)
  ln_kernel<<<MQ / 4, blk, 0, stream>>>(tgt1, Db, n1g, n1b, tgt2);
  // 12) FFN lin1 + relu -> mid — bf16 MFMA 64-tile
  gemm_bf16_64<<<dim3(16, gy_q), blk, 0, stream>>>(tgt2, nullptr, lin1_w, lin1_b, mid, MQ, DFF_, D_, 1, 0);
  // 13) FFN lin2 -> Db — bf16 MFMA 64-tile (K=1024)
  gemm_bf16_64<<<dim3(4, gy_q), blk, 0, stream>>>(mid, nullptr, lin2_w, lin2_b, Db, MQ, 256, DFF_, 0, 0);
  // 14) out = LN(tgt2 + ffn; norm3)
  ln_kernel<<<MQ / 4, blk, 0, stream>>>(tgt2, Db, n3g, n3b, (float*)d_out);
}

// Round 15
// 506.882 us; speedup vs baseline: 1.1517x; 1.0314x over previous
//
#include <hip/hip_runtime.h>
#include <hip/hip_bf16.h>
#include <math.h>

#define D_ 256
#define HEADS_ 8
#define DH_ 32
#define LVLS_ 4
#define PTS_ 4
#define DFF_ 1024
#define LQ_ 900
#define B_ 16
#define S_ 13294
#define MQ (LQ_*B_)      // 14400
#define MV (S_*B_)       // 212704

typedef __attribute__((ext_vector_type(4))) float f32x4;
typedef __attribute__((ext_vector_type(8))) short bf16x8;

static __device__ inline ushort f2bf(float f) {
  __hip_bfloat16 h = __float2bfloat16(f);   // RNE
  union { __hip_bfloat16 h; ushort u; } c; c.h = h;
  return c.u;
}
static __device__ inline float bf2f(ushort u) {
  union { float f; uint u; } c; c.u = (uint)u << 16; return c.f;
}

#define GP 40   // LDS pitch in ushorts (80 B rows)

// ---------------- bf16-MFMA GEMM, 128x128 tile, 8 waves, BK=32 ----------------
// Best measured on the value projection (136 us).
__global__ __launch_bounds__(512) void gemm_bf16_512(
    const float* __restrict__ A, const float* __restrict__ Wm,
    const float* __restrict__ bias, float* __restrict__ Y,
    int M, int N, int K, int relu, int outbf)
{
  __shared__ ushort As[128 * GP];   // 10 KB
  __shared__ ushort Ws[128 * GP];   // 10 KB
  const int tid  = threadIdx.x;
  const int lane = tid & 63;
  const int wid  = tid >> 6;          // 0..7
  const int wr   = wid >> 1;          // 0..3: 32-row band
  const int wc   = wid & 1;           // 0..1: 64-col half
  const int fr = lane & 15;
  const int fk = (lane >> 4) << 3;
  const int m0 = blockIdx.y * 128, n0 = blockIdx.x * 128;

  f32x4 acc[2][4];
  const f32x4 zero = {0.f, 0.f, 0.f, 0.f};
#pragma unroll
  for (int i = 0; i < 2; ++i)
#pragma unroll
    for (int j = 0; j < 4; ++j) acc[i][j] = zero;

  const int srow = tid >> 2;
  const int skh  = (tid & 3) << 3;
  int agr = m0 + srow; if (agr > M - 1) agr = M - 1;
  const float* apb = A  + (size_t)agr * K + skh;
  const float* wpb = Wm + (size_t)(n0 + srow) * K + skh;

  float4 pa[2], pw[2];
  pa[0] = *(const float4*)(apb);     pa[1] = *(const float4*)(apb + 4);
  pw[0] = *(const float4*)(wpb);     pw[1] = *(const float4*)(wpb + 4);

  for (int k0 = 0; k0 < K; k0 += 32) {
    if (k0) __syncthreads();
    ushort tmp[8] __attribute__((aligned(16)));
    tmp[0]=f2bf(pa[0].x); tmp[1]=f2bf(pa[0].y); tmp[2]=f2bf(pa[0].z); tmp[3]=f2bf(pa[0].w);
    tmp[4]=f2bf(pa[1].x); tmp[5]=f2bf(pa[1].y); tmp[6]=f2bf(pa[1].z); tmp[7]=f2bf(pa[1].w);
    *(bf16x8*)&As[srow*GP + skh] = *(const bf16x8*)tmp;
    tmp[0]=f2bf(pw[0].x); tmp[1]=f2bf(pw[0].y); tmp[2]=f2bf(pw[0].z); tmp[3]=f2bf(pw[0].w);
    tmp[4]=f2bf(pw[1].x); tmp[5]=f2bf(pw[1].y); tmp[6]=f2bf(pw[1].z); tmp[7]=f2bf(pw[1].w);
    *(bf16x8*)&Ws[srow*GP + skh] = *(const bf16x8*)tmp;
    if (k0 + 32 < K) {
      const float* ap = apb + k0 + 32;
      const float* wp = wpb + k0 + 32;
      pa[0] = *(const float4*)(ap);  pa[1] = *(const float4*)(ap + 4);
      pw[0] = *(const float4*)(wp);  pw[1] = *(const float4*)(wp + 4);
    }
    __syncthreads();

    bf16x8 ar[2], br[4];
#pragma unroll
    for (int i = 0; i < 2; ++i)
      ar[i] = *(const bf16x8*)&As[(wr*32 + i*16 + fr)*GP + fk];
#pragma unroll
    for (int j = 0; j < 4; ++j)
      br[j] = *(const bf16x8*)&Ws[(wc*64 + j*16 + fr)*GP + fk];
#pragma unroll
    for (int i = 0; i < 2; ++i)
#pragma unroll
      for (int j = 0; j < 4; ++j)
        acc[i][j] = __builtin_amdgcn_mfma_f32_16x16x32_bf16(ar[i], br[j], acc[i][j], 0, 0, 0);
  }

  const int gcolbase = n0 + wc * 64 + fr;
  float bias4[4];
#pragma unroll
  for (int j = 0; j < 4; ++j) bias4[j] = bias[gcolbase + j * 16];
#pragma unroll
  for (int i = 0; i < 2; ++i) {
    const int rb = m0 + wr * 32 + i * 16 + (lane >> 4) * 4;
#pragma unroll
    for (int r = 0; r < 4; ++r) {
      const int grow = rb + r;
      if (grow < M) {
#pragma unroll
        for (int j = 0; j < 4; ++j) {
          float v = acc[i][j][r] + bias4[j];
          if (relu) v = fmaxf(v, 0.f);
          if (outbf) ((ushort*)Y)[(size_t)grow * N + gcolbase + j * 16] = f2bf(v);
          else       Y[(size_t)grow * N + gcolbase + j * 16] = v;
        }
      }
    }
  }
}

// ---------------- bf16-MFMA GEMM, 64x64 tile ----------------
// x2_nlim: add X2 to the A-tile only for blocks with n0 < x2_nlim
// (used by the merged QKV projection: Q,K get pos, V doesn't).
__global__ __launch_bounds__(256) void gemm_bf16_64(
    const float* __restrict__ A, const float* __restrict__ X2,
    const float* __restrict__ Wm, const float* __restrict__ bias,
    float* __restrict__ Y, int M, int N, int K, int relu, int outbf, int x2_nlim)
{
  __shared__ ushort As[64 * GP];   // 5 KB
  __shared__ ushort Ws[64 * GP];   // 5 KB
  const int tid  = threadIdx.x;
  const int lane = tid & 63;
  const int wid  = tid >> 6;
  const int wr = wid >> 1, wc = wid & 1;
  const int fr = lane & 15;
  const int fk = (lane >> 4) << 3;
  const int m0 = blockIdx.y * 64, n0 = blockIdx.x * 64;

  f32x4 acc[2][2];
  const f32x4 zero = {0.f, 0.f, 0.f, 0.f};
#pragma unroll
  for (int i = 0; i < 2; ++i)
#pragma unroll
    for (int j = 0; j < 2; ++j) acc[i][j] = zero;

  const int srow = tid >> 1;          // 0..127
  const int skh  = (tid & 1) << 4;    // 0 or 16
  const bool isA = srow < 64;
  const float* src;
  const float* src2 = nullptr;
  ushort* dst;
  if (isA) {
    int gr = m0 + srow; if (gr > M - 1) gr = M - 1;
    src = A + (size_t)gr * K + skh;
    if (X2 && n0 < x2_nlim) src2 = X2 + (size_t)gr * K + skh;
    dst = &As[srow * GP + skh];
  } else {
    src = Wm + (size_t)(n0 + srow - 64) * K + skh;
    dst = &Ws[(srow - 64) * GP + skh];
  }

  float4 pd[4];
#pragma unroll
  for (int i2 = 0; i2 < 4; ++i2) pd[i2] = *(const float4*)(src + i2 * 4);
  if (src2) {
#pragma unroll
    for (int i2 = 0; i2 < 4; ++i2) {
      const float4 u = *(const float4*)(src2 + i2 * 4);
      pd[i2].x += u.x; pd[i2].y += u.y; pd[i2].z += u.z; pd[i2].w += u.w;
    }
  }

  for (int k0 = 0; k0 < K; k0 += 32) {
    if (k0) __syncthreads();
    ushort tmp[16] __attribute__((aligned(16)));
#pragma unroll
    for (int i2 = 0; i2 < 4; ++i2) {
      tmp[i2*4+0] = f2bf(pd[i2].x); tmp[i2*4+1] = f2bf(pd[i2].y);
      tmp[i2*4+2] = f2bf(pd[i2].z); tmp[i2*4+3] = f2bf(pd[i2].w);
    }
    *(bf16x8*)(dst)     = *(const bf16x8*)&tmp[0];
    *(bf16x8*)(dst + 8) = *(const bf16x8*)&tmp[8];
    if (k0 + 32 < K) {
      const float* s = src + k0 + 32;
#pragma unroll
      for (int i2 = 0; i2 < 4; ++i2) pd[i2] = *(const float4*)(s + i2 * 4);
      if (src2) {
        const float* s2 = src2 + k0 + 32;
#pragma unroll
        for (int i2 = 0; i2 < 4; ++i2) {
          const float4 u = *(const float4*)(s2 + i2 * 4);
          pd[i2].x += u.x; pd[i2].y += u.y; pd[i2].z += u.z; pd[i2].w += u.w;
        }
      }
    }
    __syncthreads();

    bf16x8 af[2], bf[2];
#pragma unroll
    for (int i = 0; i < 2; ++i)
      af[i] = *(const bf16x8*)&As[(wr*32 + i*16 + fr)*GP + fk];
#pragma unroll
    for (int j = 0; j < 2; ++j)
      bf[j] = *(const bf16x8*)&Ws[(wc*32 + j*16 + fr)*GP + fk];
#pragma unroll
    for (int i = 0; i < 2; ++i)
#pragma unroll
      for (int j = 0; j < 2; ++j)
        acc[i][j] = __builtin_amdgcn_mfma_f32_16x16x32_bf16(af[i], bf[j], acc[i][j], 0, 0, 0);
  }

  const int gcolbase = n0 + wc * 32 + fr;
  float bias2[2];
#pragma unroll
  for (int j = 0; j < 2; ++j) bias2[j] = bias[gcolbase + j * 16];
#pragma unroll
  for (int i = 0; i < 2; ++i) {
    const int rb = m0 + wr * 32 + i * 16 + (lane >> 4) * 4;
#pragma unroll
    for (int r = 0; r < 4; ++r) {
      const int grow = rb + r;
      if (grow < M) {
#pragma unroll
        for (int j = 0; j < 2; ++j) {
          float v = acc[i][j][r] + bias2[j];
          if (relu) v = fmaxf(v, 0.f);
          if (outbf) ((ushort*)Y)[(size_t)grow * N + gcolbase + j * 16] = f2bf(v);
          else       Y[(size_t)grow * N + gcolbase + j * 16] = v;
        }
      }
    }
  }
}

// ---------------- dual-W bf16 GEMM, 64x64 tile: two weight/output sets ----------------
// blocks bx < nb1 compute Y1 = (A+X2) @ W1^T + b1 (N1 cols);
// blocks bx >= nb1 compute Y2 = (A+X2) @ W2^T + b2 (N2 cols).
// One pass over A/X2 for both projections (steps 7+8 fused).
__global__ __launch_bounds__(256) void gemm_dual_64(
    const float* __restrict__ A, const float* __restrict__ X2,
    const float* __restrict__ W1, const float* __restrict__ b1,
    float* __restrict__ Y1, int N1, int nb1,
    const float* __restrict__ W2, const float* __restrict__ b2,
    float* __restrict__ Y2, int N2, int M, int K)
{
  __shared__ ushort As[64 * GP];
  __shared__ ushort Ws[64 * GP];
  const int tid  = threadIdx.x;
  const int lane = tid & 63;
  const int wid  = tid >> 6;
  const int wr = wid >> 1, wc = wid & 1;
  const int fr = lane & 15;
  const int fk = (lane >> 4) << 3;
  const int bx = blockIdx.x;
  const bool second = bx >= nb1;
  const float* Wm  = second ? W2 : W1;
  const float* bia = second ? b2 : b1;
  float* Y         = second ? Y2 : Y1;
  const int N      = second ? N2 : N1;
  const int n0     = (second ? (bx - nb1) : bx) * 64;
  const int m0     = blockIdx.y * 64;

  f32x4 acc[2][2];
  const f32x4 zero = {0.f, 0.f, 0.f, 0.f};
#pragma unroll
  for (int i = 0; i < 2; ++i)
#pragma unroll
    for (int j = 0; j < 2; ++j) acc[i][j] = zero;

  const int srow = tid >> 1;
  const int skh  = (tid & 1) << 4;
  const bool isA = srow < 64;
  const float* src;
  const float* src2 = nullptr;
  ushort* dst;
  if (isA) {
    int gr = m0 + srow; if (gr > M - 1) gr = M - 1;
    src = A + (size_t)gr * K + skh;
    if (X2) src2 = X2 + (size_t)gr * K + skh;
    dst = &As[srow * GP + skh];
  } else {
    src = Wm + (size_t)(n0 + srow - 64) * K + skh;
    dst = &Ws[(srow - 64) * GP + skh];
  }

  float4 pd[4];
#pragma unroll
  for (int i2 = 0; i2 < 4; ++i2) pd[i2] = *(const float4*)(src + i2 * 4);
  if (src2) {
#pragma unroll
    for (int i2 = 0; i2 < 4; ++i2) {
      const float4 u = *(const float4*)(src2 + i2 * 4);
      pd[i2].x += u.x; pd[i2].y += u.y; pd[i2].z += u.z; pd[i2].w += u.w;
    }
  }

  for (int k0 = 0; k0 < K; k0 += 32) {
    if (k0) __syncthreads();
    ushort tmp[16] __attribute__((aligned(16)));
#pragma unroll
    for (int i2 = 0; i2 < 4; ++i2) {
      tmp[i2*4+0] = f2bf(pd[i2].x); tmp[i2*4+1] = f2bf(pd[i2].y);
      tmp[i2*4+2] = f2bf(pd[i2].z); tmp[i2*4+3] = f2bf(pd[i2].w);
    }
    *(bf16x8*)(dst)     = *(const bf16x8*)&tmp[0];
    *(bf16x8*)(dst + 8) = *(const bf16x8*)&tmp[8];
    if (k0 + 32 < K) {
      const float* s = src + k0 + 32;
#pragma unroll
      for (int i2 = 0; i2 < 4; ++i2) pd[i2] = *(const float4*)(s + i2 * 4);
      if (src2) {
        const float* s2 = src2 + k0 + 32;
#pragma unroll
        for (int i2 = 0; i2 < 4; ++i2) {
          const float4 u = *(const float4*)(s2 + i2 * 4);
          pd[i2].x += u.x; pd[i2].y += u.y; pd[i2].z += u.z; pd[i2].w += u.w;
        }
      }
    }
    __syncthreads();

    bf16x8 af[2], bf[2];
#pragma unroll
    for (int i = 0; i < 2; ++i)
      af[i] = *(const bf16x8*)&As[(wr*32 + i*16 + fr)*GP + fk];
#pragma unroll
    for (int j = 0; j < 2; ++j)
      bf[j] = *(const bf16x8*)&Ws[(wc*32 + j*16 + fr)*GP + fk];
#pragma unroll
    for (int i = 0; i < 2; ++i)
#pragma unroll
      for (int j = 0; j < 2; ++j)
        acc[i][j] = __builtin_amdgcn_mfma_f32_16x16x32_bf16(af[i], bf[j], acc[i][j], 0, 0, 0);
  }

  const int gcolbase = n0 + wc * 32 + fr;
  float bias2[2];
#pragma unroll
  for (int j = 0; j < 2; ++j) bias2[j] = bia[gcolbase + j * 16];
#pragma unroll
  for (int i = 0; i < 2; ++i) {
    const int rb = m0 + wr * 32 + i * 16 + (lane >> 4) * 4;
#pragma unroll
    for (int r = 0; r < 4; ++r) {
      const int grow = rb + r;
      if (grow < M) {
#pragma unroll
        for (int j = 0; j < 2; ++j)
          Y[(size_t)grow * N + gcolbase + j * 16] = acc[i][j][r] + bias2[j];
      }
    }
  }
}

// ---------------- self-attention: MFMA flash (swapped QK^T), bf16, QB=128 ----------------
// QKV: [MQ, 768] (Q at +0, K at +256, V at +512).
#define QB 128
#define KB 64
#define KP 40   // Ks / P pitch (ushort)
#define VP 72   // Vt pitch (ushort)
__global__ __launch_bounds__(256) void attn_mfma_kernel(
    const float* __restrict__ QKV, float* __restrict__ O)
{
  __shared__ ushort Ks[KB * KP];       // 5120 B
  __shared__ ushort Vt[DH_ * VP];      // 4608 B
  __shared__ ushort Pl[4][32 * KP];    // 10240 B
  const int tid  = threadIdx.x;
  const int lane = tid & 63;
  const int w    = tid >> 6;
  const int bh = blockIdx.y;
  const int h  = bh & (HEADS_ - 1);
  const int b  = bh >> 3;
  const int q0 = blockIdx.x * QB;
  const int lq = lane & 15;
  const int lg = lane >> 4;
  const float scale = 0.17677669529663687f;
  const f32x4 zero4 = {0.f, 0.f, 0.f, 0.f};

  bf16x8 qf[2];
#pragma unroll
  for (int s = 0; s < 2; ++s) {
    int qg = q0 + w * 32 + s * 16 + lq; if (qg > LQ_ - 1) qg = LQ_ - 1;
    const float* qp = QKV + ((size_t)qg * B_ + b) * 768 + h * DH_ + lg * 8;
    const float4 a = *(const float4*)qp;
    const float4 c = *(const float4*)(qp + 4);
    ushort t[8] __attribute__((aligned(16)));
    t[0]=f2bf(a.x*scale); t[1]=f2bf(a.y*scale); t[2]=f2bf(a.z*scale); t[3]=f2bf(a.w*scale);
    t[4]=f2bf(c.x*scale); t[5]=f2bf(c.y*scale); t[6]=f2bf(c.z*scale); t[7]=f2bf(c.w*scale);
    qf[s] = *(const bf16x8*)t;
  }

  float mrow[2] = {-1e30f, -1e30f}, srow[2] = {0.f, 0.f};
  f32x4 oacc[2][2];
  oacc[0][0] = zero4; oacc[0][1] = zero4; oacc[1][0] = zero4; oacc[1][1] = zero4;

  const int nkt = (LQ_ + KB - 1) / KB;   // 15
  for (int t = 0; t < nkt; ++t) {
    const int k0 = t * KB;
    const int klen = (LQ_ - k0) < KB ? (LQ_ - k0) : KB;
    if (t) __syncthreads();
    // ---- stage K ----
    {
      const int kk  = tid >> 2;
      const int dh0 = (tid & 3) * 8;
      ushort kb[8] __attribute__((aligned(16)));
      if (kk < klen) {
        const float* kp = QKV + ((size_t)(k0 + kk) * B_ + b) * 768 + 256 + h * DH_ + dh0;
        const float4 k1 = *(const float4*)kp;
        const float4 k2 = *(const float4*)(kp + 4);
        kb[0]=f2bf(k1.x); kb[1]=f2bf(k1.y); kb[2]=f2bf(k1.z); kb[3]=f2bf(k1.w);
        kb[4]=f2bf(k2.x); kb[5]=f2bf(k2.y); kb[6]=f2bf(k2.z); kb[7]=f2bf(k2.w);
      } else {
#pragma unroll
        for (int j = 0; j < 8; ++j) kb[j] = 0;
      }
      *(bf16x8*)&Ks[kk * KP + dh0] = *(const bf16x8*)kb;
    }
    // ---- stage V transposed (packed u32 writes) ----
    {
      const int kk2  = (tid >> 3) << 1;     // 0,2,..,62
      const int dh0v = (tid & 7) * 4;       // 0,4,..,28
      float v0[4] = {0.f, 0.f, 0.f, 0.f};
      float v1[4] = {0.f, 0.f, 0.f, 0.f};
      if (kk2 < klen) {
        const float4 x = *(const float4*)(QKV + ((size_t)(k0 + kk2) * B_ + b) * 768 + 512 + h * DH_ + dh0v);
        v0[0] = x.x; v0[1] = x.y; v0[2] = x.z; v0[3] = x.w;
      }
      if (kk2 + 1 < klen) {
        const float4 x = *(const float4*)(QKV + ((size_t)(k0 + kk2 + 1) * B_ + b) * 768 + 512 + h * DH_ + dh0v);
        v1[0] = x.x; v1[1] = x.y; v1[2] = x.z; v1[3] = x.w;
      }
#pragma unroll
      for (int j = 0; j < 4; ++j) {
        const uint pk = (uint)f2bf(v0[j]) | ((uint)f2bf(v1[j]) << 16);
        *(uint*)&Vt[(dh0v + j) * VP + kk2] = pk;
      }
    }
    __syncthreads();

    float cfac[2];
#pragma unroll
    for (int s = 0; s < 2; ++s) {
      f32x4 sc[4];
#pragma unroll
      for (int j = 0; j < 4; ++j) {
        const bf16x8 kf = *(const bf16x8*)&Ks[(j * 16 + lq) * KP + lg * 8];
        sc[j] = __builtin_amdgcn_mfma_f32_16x16x32_bf16(kf, qf[s], zero4, 0, 0, 0);
      }
      if (klen < KB) {
#pragma unroll
        for (int j = 0; j < 4; ++j)
#pragma unroll
          for (int r = 0; r < 4; ++r)
            if (j * 16 + lg * 4 + r >= klen) sc[j][r] = -1e30f;
      }
      float tmax = -1e30f;
#pragma unroll
      for (int j = 0; j < 4; ++j)
#pragma unroll
        for (int r = 0; r < 4; ++r) tmax = fmaxf(tmax, sc[j][r]);
      tmax = fmaxf(tmax, __shfl_xor(tmax, 16, 64));
      tmax = fmaxf(tmax, __shfl_xor(tmax, 32, 64));
      const float mnew = fmaxf(mrow[s], tmax);
      cfac[s] = __expf(mrow[s] - mnew);
      mrow[s] = mnew;
      float tsum = 0.f;
#pragma unroll
      for (int j = 0; j < 4; ++j)
#pragma unroll
        for (int r = 0; r < 4; ++r) {
          const float p = __expf(sc[j][r] - mnew);
          sc[j][r] = p; tsum += p;
        }
      tsum += __shfl_xor(tsum, 16, 64);
      tsum += __shfl_xor(tsum, 32, 64);
      srow[s] = srow[s] * cfac[s] + tsum;
#pragma unroll
      for (int j = 0; j < 4; ++j) {
        const uint lo = (uint)f2bf(sc[j][0]) | ((uint)f2bf(sc[j][1]) << 16);
        const uint hi = (uint)f2bf(sc[j][2]) | ((uint)f2bf(sc[j][3]) << 16);
        *(uint*)&Pl[w][(s * 16 + lq) * KP + j * 16 + lg * 4]     = lo;
        *(uint*)&Pl[w][(s * 16 + lq) * KP + j * 16 + lg * 4 + 2] = hi;
      }
    }
#pragma unroll
    for (int s = 0; s < 2; ++s) {
      float crow[4];
#pragma unroll
      for (int r = 0; r < 4; ++r) crow[r] = __shfl(cfac[s], lg * 4 + r, 64);
#pragma unroll
      for (int nt = 0; nt < 2; ++nt)
#pragma unroll
        for (int r = 0; r < 4; ++r) oacc[s][nt][r] *= crow[r];
#pragma unroll
      for (int ks = 0; ks < 2; ++ks) {
        const bf16x8 pf = *(const bf16x8*)&Pl[w][(s * 16 + lq) * KP + ks * 32 + lg * 8];
#pragma unroll
        for (int nt = 0; nt < 2; ++nt) {
          const bf16x8 vf = *(const bf16x8*)&Vt[(nt * 16 + lq) * VP + ks * 32 + lg * 8];
          oacc[s][nt] = __builtin_amdgcn_mfma_f32_16x16x32_bf16(pf, vf, oacc[s][nt], 0, 0, 0);
        }
      }
    }
  }
#pragma unroll
  for (int s = 0; s < 2; ++s) {
    float sinv[4];
#pragma unroll
    for (int r = 0; r < 4; ++r) {
      const float sr = __shfl(srow[s], lg * 4 + r, 64);
      sinv[r] = 1.f / sr;
    }
#pragma unroll
    for (int r = 0; r < 4; ++r) {
      const int qg = q0 + w * 32 + s * 16 + lg * 4 + r;
      if (qg < LQ_) {
        float* op = O + ((size_t)qg * B_ + b) * 256 + h * DH_;
        op[lq]      = oacc[s][0][r] * sinv[r];
        op[16 + lq] = oacc[s][1][r] * sinv[r];
      }
    }
  }
}

// ---------------- residual + LayerNorm: Y = LN(X + R) * g + b ----------------
__global__ __launch_bounds__(256) void ln_kernel(
    const float* __restrict__ X, const float* __restrict__ R,
    const float* __restrict__ g, const float* __restrict__ be,
    float* __restrict__ Y)
{
  const int row  = blockIdx.x * 4 + (threadIdx.x >> 6);
  const int lane = threadIdx.x & 63;
  const size_t base = (size_t)row * D_ + lane * 4;
  float4 v = *(const float4*)(X + base);
  const float4 rv = *(const float4*)(R + base);
  v.x += rv.x; v.y += rv.y; v.z += rv.z; v.w += rv.w;

  float sum = (v.x + v.y) + (v.z + v.w);
#pragma unroll
  for (int o = 32; o > 0; o >>= 1) sum += __shfl_xor(sum, o, 64);
  const float mean = sum * (1.f / D_);
  const float4 d = make_float4(v.x - mean, v.y - mean, v.z - mean, v.w - mean);
  float sq = (d.x * d.x + d.y * d.y) + (d.z * d.z + d.w * d.w);
#pragma unroll
  for (int o = 32; o > 0; o >>= 1) sq += __shfl_xor(sq, o, 64);
  const float rs = rsqrtf(sq * (1.f / D_) + 1e-5f);

  const float4 gv = *(const float4*)(g + lane * 4);
  const float4 bv = *(const float4*)(be + lane * 4);
  float4 o4;
  o4.x = d.x * rs * gv.x + bv.x;
  o4.y = d.y * rs * gv.y + bv.y;
  o4.z = d.z * rs * gv.z + bv.z;
  o4.w = d.w * rs * gv.w + bv.w;
  *(float4*)(Y + base) = o4;
}

// ---------------- MSDeformAttn sampling (bf16 value; 4 threads per (q,b,h)) ----------------
__global__ __launch_bounds__(256) void msdeform_kernel(
    const float* __restrict__ refp, const float* __restrict__ offb,
    const float* __restrict__ awb, const ushort* __restrict__ value,
    float* __restrict__ out)
{
  const int t  = blockIdx.x * 256 + threadIdx.x;   // < MQ*HEADS_*4
  const int dq = t & 3;            // dh quarter: 8 floats
  const int h  = (t >> 2) & 7;
  const int u  = t >> 5;           // b*LQ_ + q
  const int b  = u / LQ_;
  const int q  = u - b * LQ_;
  const int r  = q * B_ + b;

  float aw[LVLS_ * PTS_];
  const float* ap = awb + (size_t)r * 128 + h * 16;
  float m = -1e30f;
#pragma unroll
  for (int i = 0; i < 16; ++i) { aw[i] = ap[i]; m = fmaxf(m, aw[i]); }
  float s = 0.f;
#pragma unroll
  for (int i = 0; i < 16; ++i) { aw[i] = __expf(aw[i] - m); s += aw[i]; }
  const float inv = 1.f / s;
#pragma unroll
  for (int i = 0; i < 16; ++i) aw[i] *= inv;

  float o[8] = {};
  const int HH[4] = {100, 50, 25, 13};
  const int WW[4] = {100, 50, 25, 13};
  const int ST[4] = {0, 10000, 12500, 13125};
  const float* orow = offb + (size_t)r * 256 + h * (LVLS_ * PTS_ * 2);
  const int dh0 = h * DH_ + dq * 8;

  for (int l = 0; l < LVLS_; ++l) {
    const float4 rf = *(const float4*)(refp + (((size_t)q * B_ + b) * LVLS_ + l) * 4);
    const int W_ = WW[l], H_ = HH[l], s0 = ST[l];
    for (int p = 0; p < PTS_; ++p) {
      const float ox = orow[(l * PTS_ + p) * 2 + 0];
      const float oy = orow[(l * PTS_ + p) * 2 + 1];
      const float lx = rf.x + ox * 0.125f * rf.z;
      const float ly = rf.y + oy * 0.125f * rf.w;
      const float x = lx * W_ - 0.5f;
      const float y = ly * H_ - 0.5f;
      const float x0f = floorf(x), y0f = floorf(y);
      const float wx = x - x0f, wy = y - y0f;
      const int x0 = (int)x0f, y0 = (int)y0f;
      const float a = aw[l * PTS_ + p];
      const float cw[4] = {(1.f - wx) * (1.f - wy) * a, wx * (1.f - wy) * a,
                           (1.f - wx) * wy * a,         wx * wy * a};
      const int cx[4] = {x0, x0 + 1, x0, x0 + 1};
      const int cy[4] = {y0, y0, y0 + 1, y0 + 1};
#pragma unroll
      for (int c = 0; c < 4; ++c) {
        const int xi = cx[c], yi = cy[c];
        if (xi >= 0 && xi < W_ && yi >= 0 && yi < H_) {
          const ushort* vp = value + ((size_t)(s0 + yi * W_ + xi) * B_ + b) * 256 + dh0;
          const float w = cw[c];
          const bf16x8 vv = *(const bf16x8*)vp;   // 16 B
#pragma unroll
          for (int j = 0; j < 8; ++j)
            o[j] = fmaf(w, bf2f(((const ushort*)&vv)[j]), o[j]);
        }
      }
    }
  }
  float* op = out + (size_t)r * 256 + dh0;
  float4 x1; x1.x = o[0]; x1.y = o[1]; x1.z = o[2]; x1.w = o[3];
  float4 x2; x2.x = o[4]; x2.y = o[5]; x2.z = o[6]; x2.w = o[7];
  *(float4*)op = x1;
  *(float4*)(op + 4) = x2;
}

extern "C" void kernel_launch(void* const* d_in, const int* in_sizes, int n_in,
                              void* d_out, int out_size, void* d_ws, size_t ws_size,
                              hipStream_t stream) {
  const float* tgt       = (const float*)d_in[0];
  const float* pos       = (const float*)d_in[1];
  const float* refp      = (const float*)d_in[2];
  const float* memory    = (const float*)d_in[3];
  const float* in_proj_w = (const float*)d_in[6];
  const float* in_proj_b = (const float*)d_in[7];
  const float* sa_out_w  = (const float*)d_in[8];
  const float* sa_out_b  = (const float*)d_in[9];
  const float* off_w     = (const float*)d_in[10];
  const float* off_b     = (const float*)d_in[11];
  const float* aw_w      = (const float*)d_in[12];
  const float* aw_b      = (const float*)d_in[13];
  const float* val_w     = (const float*)d_in[14];
  const float* val_b     = (const float*)d_in[15];
  const float* ca_out_w  = (const float*)d_in[16];
  const float* ca_out_b  = (const float*)d_in[17];
  const float* lin1_w    = (const float*)d_in[18];
  const float* lin1_b    = (const float*)d_in[19];
  const float* lin2_w    = (const float*)d_in[20];
  const float* lin2_b    = (const float*)d_in[21];
  const float* n1g = (const float*)d_in[22];
  const float* n1b = (const float*)d_in[23];
  const float* n2g = (const float*)d_in[24];
  const float* n2b = (const float*)d_in[25];
  const float* n3g = (const float*)d_in[26];
  const float* n3b = (const float*)d_in[27];

  float* ws = (float*)d_ws;
  float* QKV   = ws;                               // MQ*768 (Q|K|V); later reused: offb (MQ*256) + awb (MQ*128)
  float* Cb    = QKV  + (size_t)MQ * 768;          // MQ*256
  float* Db    = Cb   + (size_t)MQ * 256;          // MQ*256
  float* tgt1  = Db   + (size_t)MQ * 256;          // MQ*256
  float* tgt2  = tgt1 + (size_t)MQ * 256;          // MQ*256
  float* big   = tgt2 + (size_t)MQ * 256;          // max(MV*128, MQ*1024) floats
  ushort* value = (ushort*)big;                    // MV*256 bf16
  float* mid   = big;    // FFN mid aliases value region (disjoint lifetimes)
  float* offb  = QKV;                              // reuse (QKV dead after attn)
  float* awb   = QKV + (size_t)MQ * 256;

  const dim3 blk(256);
  const int gy_q = (MQ + 63) / 64;        // 225
  const int gy_v128 = (MV + 127) / 128;   // 1662
  const int qtiles = (LQ_ + QB - 1) / QB; // 8

  // 1) QKV projection — one N=768 GEMM; pos added only for Q,K columns (n0<512)
  gemm_bf16_64<<<dim3(12, gy_q), blk, 0, stream>>>(tgt, pos, in_proj_w, in_proj_b, QKV, MQ, 768, D_, 0, 0, 512);
  // 2) self-attention — bf16 MFMA flash, QB=128, reads Q/K/V from QKV
  attn_mfma_kernel<<<dim3(qtiles, B_ * HEADS_), blk, 0, stream>>>(QKV, Cb);
  // 3) SA out proj
  gemm_bf16_64<<<dim3(4, gy_q), blk, 0, stream>>>(Cb, nullptr, sa_out_w, sa_out_b, Db, MQ, 256, D_, 0, 0, 0);
  // 4) tgt1 = LN(tgt + sa; norm2)
  ln_kernel<<<MQ / 4, blk, 0, stream>>>(tgt, Db, n2g, n2b, tgt1);
  // 5) value projection over memory — 128-tile / 8 waves / BK=32, bf16 out
  gemm_bf16_512<<<dim3(2, gy_v128), dim3(512), 0, stream>>>(memory, val_w, val_b, (float*)value, MV, 256, D_, 0, 1);
  // 6) sampling offsets + aw logits — fused dual-W GEMM (one pass over tgt1+pos)
  gemm_dual_64<<<dim3(6, gy_q), blk, 0, stream>>>(tgt1, pos, off_w, off_b, offb, 256, 4, aw_w, aw_b, awb, 128, MQ, D_);
  // 7) deformable sampling -> Cb  (bf16 value gather)
  msdeform_kernel<<<(MQ * HEADS_ * 4 + 255) / 256, blk, 0, stream>>>(refp, offb, awb, value, Cb);
  // 8) CA out proj
  gemm_bf16_64<<<dim3(4, gy_q), blk, 0, stream>>>(Cb, nullptr, ca_out_w, ca_out_b, Db, MQ, 256, D_, 0, 0, 0);
  // 9) tgt2 = LN(tgt1 + ca; norm1)
  ln_kernel<<<MQ / 4, blk, 0, stream>>>(tgt1, Db, n1g, n1b, tgt2);
  // 10) FFN lin1 + relu -> mid
  gemm_bf16_64<<<dim3(16, gy_q), blk, 0, stream>>>(tgt2, nullptr, lin1_w, lin1_b, mid, MQ, DFF_, D_, 1, 0, 0);
  // 11) FFN lin2 -> Db
  gemm_bf16_64<<<dim3(4, gy_q), blk, 0, stream>>>(mid, nullptr, lin2_w, lin2_b, Db, MQ, 256, DFF_, 0, 0, 0);
  // 12) out = LN(tgt2 + ffn; norm3)
  ln_kernel<<<MQ / 4, blk, 0, stream>>>(tgt2, Db, n3g, n3b, (float*)d_out);
}

// Round 16
// 499.948 us; speedup vs baseline: 1.1676x; 1.0139x over previous
//
#include <hip/hip_runtime.h>
#include <hip/hip_bf16.h>
#include <math.h>

#define D_ 256
#define HEADS_ 8
#define DH_ 32
#define LVLS_ 4
#define PTS_ 4
#define DFF_ 1024
#define LQ_ 900
#define B_ 16
#define S_ 13294
#define MQ (LQ_*B_)      // 14400
#define MV (S_*B_)       // 212704

typedef __attribute__((ext_vector_type(4))) float f32x4;
typedef __attribute__((ext_vector_type(8))) short bf16x8;

static __device__ inline ushort f2bf(float f) {
  __hip_bfloat16 h = __float2bfloat16(f);   // RNE
  union { __hip_bfloat16 h; ushort u; } c; c.h = h;
  return c.u;
}
static __device__ inline float bf2f(ushort u) {
  union { float f; uint u; } c; c.u = (uint)u << 16; return c.f;
}
static __device__ __forceinline__ void gload16(const float* g, float* lds) {
  __builtin_amdgcn_global_load_lds(
      (const __attribute__((address_space(1))) void*)g,
      (__attribute__((address_space(3))) void*)lds,
      16, 0, 0);
}

#define GP 40   // LDS pitch in ushorts (80 B rows)

// ---------------- value-projection GEMM: global_load_lds staging ----------------
// Y(bf16) = A @ W^T + bias. A:[M,256] f32; W:[256,256] f32. 512 thr, 128x128 tile.
// A,W staged as RAW F32 via global_load_lds width-16 (no VGPR round-trip);
// f32->bf16 conversion happens during fragment read (VALU idle there).
// Swizzle (both-sides involution): lane l of a chunk writes LDS linearly
// (row l>>3, slot l&7); SOURCE col16 = (l&7)^(l>>3); READ slot' = slot^(row&7).
// -> fragment ds_reads spread 8 slots x 4 banks = 2-way (free).
__global__ __launch_bounds__(512) void gemm_val_gld(
    const float* __restrict__ A, const float* __restrict__ Wm,
    const float* __restrict__ bias, ushort* __restrict__ Y, int M)
{
  __shared__ float AsF[128 * 32];   // 16 KB
  __shared__ float WsF[128 * 32];   // 16 KB
  const int tid  = threadIdx.x;
  const int lane = tid & 63;
  const int wid  = tid >> 6;          // 0..7
  const int wr   = wid >> 1;          // 0..3: 32-row band
  const int wc   = wid & 1;           // 0..1: 64-col half
  const int fr = lane & 15;
  const int lg = lane >> 4;           // 0..3
  const int m0 = blockIdx.y * 128, n0 = blockIdx.x * 128;

  f32x4 acc[2][4];
  const f32x4 zero = {0.f, 0.f, 0.f, 0.f};
#pragma unroll
  for (int i = 0; i < 2; ++i)
#pragma unroll
    for (int j = 0; j < 4; ++j) acc[i][j] = zero;

  // staging lane geometry (per 8-row chunk of 1024 B)
  const int rin   = lane >> 3;              // row in chunk 0..7
  const int colx  = ((lane & 7) ^ rin) * 4; // pre-swizzled source col (f32)
  // fragment read geometry
  const int x  = fr & 7;                    // read-side XOR
  const int sb = lg * 2;                    // base 16B-slot of this lane's k-slice

  for (int k0 = 0; k0 < 256; k0 += 32) {
    if (k0) __syncthreads();
    // ---- stage: 2 chunks of A + 2 chunks of W per wave, width-16 direct-to-LDS ----
#pragma unroll
    for (int c2 = 0; c2 < 2; ++c2) {
      const int c  = (wid << 1) | c2;       // chunk 0..15 (8 rows each)
      const int rb = c * 8 + rin;           // tile row 0..127
      int ar = m0 + rb; if (ar > M - 1) ar = M - 1;
      gload16(A  + (size_t)ar * 256 + k0 + colx, &AsF[c * 256]);
      gload16(Wm + (size_t)(n0 + rb) * 256 + k0 + colx, &WsF[c * 256]);
    }
    __syncthreads();   // drains vmcnt (LDS writes) + sync

    // ---- fragment read (swizzled) + cvt + MFMA ----
    bf16x8 ar8[2], br8[4];
#pragma unroll
    for (int i = 0; i < 2; ++i) {
      const float* base = &AsF[(wr * 32 + i * 16 + fr) * 32];
      const float4 lo = *(const float4*)(base + ((sb ^ x) << 2));
      const float4 hi = *(const float4*)(base + (((sb + 1) ^ x) << 2));
      ushort t[8] __attribute__((aligned(16)));
      t[0]=f2bf(lo.x); t[1]=f2bf(lo.y); t[2]=f2bf(lo.z); t[3]=f2bf(lo.w);
      t[4]=f2bf(hi.x); t[5]=f2bf(hi.y); t[6]=f2bf(hi.z); t[7]=f2bf(hi.w);
      ar8[i] = *(const bf16x8*)t;
    }
#pragma unroll
    for (int j = 0; j < 4; ++j) {
      const float* base = &WsF[(wc * 64 + j * 16 + fr) * 32];
      const float4 lo = *(const float4*)(base + ((sb ^ x) << 2));
      const float4 hi = *(const float4*)(base + (((sb + 1) ^ x) << 2));
      ushort t[8] __attribute__((aligned(16)));
      t[0]=f2bf(lo.x); t[1]=f2bf(lo.y); t[2]=f2bf(lo.z); t[3]=f2bf(lo.w);
      t[4]=f2bf(hi.x); t[5]=f2bf(hi.y); t[6]=f2bf(hi.z); t[7]=f2bf(hi.w);
      br8[j] = *(const bf16x8*)t;
    }
#pragma unroll
    for (int i = 0; i < 2; ++i)
#pragma unroll
      for (int j = 0; j < 4; ++j)
        acc[i][j] = __builtin_amdgcn_mfma_f32_16x16x32_bf16(ar8[i], br8[j], acc[i][j], 0, 0, 0);
  }

  // epilogue: C/D layout col = lane&15, row = (lane>>4)*4 + reg; bf16 out
  const int gcolbase = n0 + wc * 64 + fr;
  float bias4[4];
#pragma unroll
  for (int j = 0; j < 4; ++j) bias4[j] = bias[gcolbase + j * 16];
#pragma unroll
  for (int i = 0; i < 2; ++i) {
    const int rb = m0 + wr * 32 + i * 16 + lg * 4;
#pragma unroll
    for (int r = 0; r < 4; ++r) {
      const int grow = rb + r;
      if (grow < M) {
#pragma unroll
        for (int j = 0; j < 4; ++j)
          Y[(size_t)grow * 256 + gcolbase + j * 16] = f2bf(acc[i][j][r] + bias4[j]);
      }
    }
  }
}

// ---------------- bf16-MFMA GEMM, 64x64 tile ----------------
// x2_nlim: add X2 to the A-tile only for blocks with n0 < x2_nlim.
__global__ __launch_bounds__(256) void gemm_bf16_64(
    const float* __restrict__ A, const float* __restrict__ X2,
    const float* __restrict__ Wm, const float* __restrict__ bias,
    float* __restrict__ Y, int M, int N, int K, int relu, int outbf, int x2_nlim)
{
  __shared__ ushort As[64 * GP];   // 5 KB
  __shared__ ushort Ws[64 * GP];   // 5 KB
  const int tid  = threadIdx.x;
  const int lane = tid & 63;
  const int wid  = tid >> 6;
  const int wr = wid >> 1, wc = wid & 1;
  const int fr = lane & 15;
  const int fk = (lane >> 4) << 3;
  const int m0 = blockIdx.y * 64, n0 = blockIdx.x * 64;

  f32x4 acc[2][2];
  const f32x4 zero = {0.f, 0.f, 0.f, 0.f};
#pragma unroll
  for (int i = 0; i < 2; ++i)
#pragma unroll
    for (int j = 0; j < 2; ++j) acc[i][j] = zero;

  const int srow = tid >> 1;          // 0..127
  const int skh  = (tid & 1) << 4;    // 0 or 16
  const bool isA = srow < 64;
  const float* src;
  const float* src2 = nullptr;
  ushort* dst;
  if (isA) {
    int gr = m0 + srow; if (gr > M - 1) gr = M - 1;
    src = A + (size_t)gr * K + skh;
    if (X2 && n0 < x2_nlim) src2 = X2 + (size_t)gr * K + skh;
    dst = &As[srow * GP + skh];
  } else {
    src = Wm + (size_t)(n0 + srow - 64) * K + skh;
    dst = &Ws[(srow - 64) * GP + skh];
  }

  float4 pd[4];
#pragma unroll
  for (int i2 = 0; i2 < 4; ++i2) pd[i2] = *(const float4*)(src + i2 * 4);
  if (src2) {
#pragma unroll
    for (int i2 = 0; i2 < 4; ++i2) {
      const float4 u = *(const float4*)(src2 + i2 * 4);
      pd[i2].x += u.x; pd[i2].y += u.y; pd[i2].z += u.z; pd[i2].w += u.w;
    }
  }

  for (int k0 = 0; k0 < K; k0 += 32) {
    if (k0) __syncthreads();
    ushort tmp[16] __attribute__((aligned(16)));
#pragma unroll
    for (int i2 = 0; i2 < 4; ++i2) {
      tmp[i2*4+0] = f2bf(pd[i2].x); tmp[i2*4+1] = f2bf(pd[i2].y);
      tmp[i2*4+2] = f2bf(pd[i2].z); tmp[i2*4+3] = f2bf(pd[i2].w);
    }
    *(bf16x8*)(dst)     = *(const bf16x8*)&tmp[0];
    *(bf16x8*)(dst + 8) = *(const bf16x8*)&tmp[8];
    if (k0 + 32 < K) {
      const float* s = src + k0 + 32;
#pragma unroll
      for (int i2 = 0; i2 < 4; ++i2) pd[i2] = *(const float4*)(s + i2 * 4);
      if (src2) {
        const float* s2 = src2 + k0 + 32;
#pragma unroll
        for (int i2 = 0; i2 < 4; ++i2) {
          const float4 u = *(const float4*)(s2 + i2 * 4);
          pd[i2].x += u.x; pd[i2].y += u.y; pd[i2].z += u.z; pd[i2].w += u.w;
        }
      }
    }
    __syncthreads();

    bf16x8 af[2], bf[2];
#pragma unroll
    for (int i = 0; i < 2; ++i)
      af[i] = *(const bf16x8*)&As[(wr*32 + i*16 + fr)*GP + fk];
#pragma unroll
    for (int j = 0; j < 2; ++j)
      bf[j] = *(const bf16x8*)&Ws[(wc*32 + j*16 + fr)*GP + fk];
#pragma unroll
    for (int i = 0; i < 2; ++i)
#pragma unroll
      for (int j = 0; j < 2; ++j)
        acc[i][j] = __builtin_amdgcn_mfma_f32_16x16x32_bf16(af[i], bf[j], acc[i][j], 0, 0, 0);
  }

  const int gcolbase = n0 + wc * 32 + fr;
  float bias2[2];
#pragma unroll
  for (int j = 0; j < 2; ++j) bias2[j] = bias[gcolbase + j * 16];
#pragma unroll
  for (int i = 0; i < 2; ++i) {
    const int rb = m0 + wr * 32 + i * 16 + (lane >> 4) * 4;
#pragma unroll
    for (int r = 0; r < 4; ++r) {
      const int grow = rb + r;
      if (grow < M) {
#pragma unroll
        for (int j = 0; j < 2; ++j) {
          float v = acc[i][j][r] + bias2[j];
          if (relu) v = fmaxf(v, 0.f);
          if (outbf) ((ushort*)Y)[(size_t)grow * N + gcolbase + j * 16] = f2bf(v);
          else       Y[(size_t)grow * N + gcolbase + j * 16] = v;
        }
      }
    }
  }
}

// ---------------- dual-W bf16 GEMM, 64x64 tile ----------------
__global__ __launch_bounds__(256) void gemm_dual_64(
    const float* __restrict__ A, const float* __restrict__ X2,
    const float* __restrict__ W1, const float* __restrict__ b1,
    float* __restrict__ Y1, int N1, int nb1,
    const float* __restrict__ W2, const float* __restrict__ b2,
    float* __restrict__ Y2, int N2, int M, int K)
{
  __shared__ ushort As[64 * GP];
  __shared__ ushort Ws[64 * GP];
  const int tid  = threadIdx.x;
  const int lane = tid & 63;
  const int wid  = tid >> 6;
  const int wr = wid >> 1, wc = wid & 1;
  const int fr = lane & 15;
  const int fk = (lane >> 4) << 3;
  const int bx = blockIdx.x;
  const bool second = bx >= nb1;
  const float* Wm  = second ? W2 : W1;
  const float* bia = second ? b2 : b1;
  float* Y         = second ? Y2 : Y1;
  const int N      = second ? N2 : N1;
  const int n0     = (second ? (bx - nb1) : bx) * 64;
  const int m0     = blockIdx.y * 64;

  f32x4 acc[2][2];
  const f32x4 zero = {0.f, 0.f, 0.f, 0.f};
#pragma unroll
  for (int i = 0; i < 2; ++i)
#pragma unroll
    for (int j = 0; j < 2; ++j) acc[i][j] = zero;

  const int srow = tid >> 1;
  const int skh  = (tid & 1) << 4;
  const bool isA = srow < 64;
  const float* src;
  const float* src2 = nullptr;
  ushort* dst;
  if (isA) {
    int gr = m0 + srow; if (gr > M - 1) gr = M - 1;
    src = A + (size_t)gr * K + skh;
    if (X2) src2 = X2 + (size_t)gr * K + skh;
    dst = &As[srow * GP + skh];
  } else {
    src = Wm + (size_t)(n0 + srow - 64) * K + skh;
    dst = &Ws[(srow - 64) * GP + skh];
  }

  float4 pd[4];
#pragma unroll
  for (int i2 = 0; i2 < 4; ++i2) pd[i2] = *(const float4*)(src + i2 * 4);
  if (src2) {
#pragma unroll
    for (int i2 = 0; i2 < 4; ++i2) {
      const float4 u = *(const float4*)(src2 + i2 * 4);
      pd[i2].x += u.x; pd[i2].y += u.y; pd[i2].z += u.z; pd[i2].w += u.w;
    }
  }

  for (int k0 = 0; k0 < K; k0 += 32) {
    if (k0) __syncthreads();
    ushort tmp[16] __attribute__((aligned(16)));
#pragma unroll
    for (int i2 = 0; i2 < 4; ++i2) {
      tmp[i2*4+0] = f2bf(pd[i2].x); tmp[i2*4+1] = f2bf(pd[i2].y);
      tmp[i2*4+2] = f2bf(pd[i2].z); tmp[i2*4+3] = f2bf(pd[i2].w);
    }
    *(bf16x8*)(dst)     = *(const bf16x8*)&tmp[0];
    *(bf16x8*)(dst + 8) = *(const bf16x8*)&tmp[8];
    if (k0 + 32 < K) {
      const float* s = src + k0 + 32;
#pragma unroll
      for (int i2 = 0; i2 < 4; ++i2) pd[i2] = *(const float4*)(s + i2 * 4);
      if (src2) {
        const float* s2 = src2 + k0 + 32;
#pragma unroll
        for (int i2 = 0; i2 < 4; ++i2) {
          const float4 u = *(const float4*)(s2 + i2 * 4);
          pd[i2].x += u.x; pd[i2].y += u.y; pd[i2].z += u.z; pd[i2].w += u.w;
        }
      }
    }
    __syncthreads();

    bf16x8 af[2], bf[2];
#pragma unroll
    for (int i = 0; i < 2; ++i)
      af[i] = *(const bf16x8*)&As[(wr*32 + i*16 + fr)*GP + fk];
#pragma unroll
    for (int j = 0; j < 2; ++j)
      bf[j] = *(const bf16x8*)&Ws[(wc*32 + j*16 + fr)*GP + fk];
#pragma unroll
    for (int i = 0; i < 2; ++i)
#pragma unroll
      for (int j = 0; j < 2; ++j)
        acc[i][j] = __builtin_amdgcn_mfma_f32_16x16x32_bf16(af[i], bf[j], acc[i][j], 0, 0, 0);
  }

  const int gcolbase = n0 + wc * 32 + fr;
  float bias2[2];
#pragma unroll
  for (int j = 0; j < 2; ++j) bias2[j] = bia[gcolbase + j * 16];
#pragma unroll
  for (int i = 0; i < 2; ++i) {
    const int rb = m0 + wr * 32 + i * 16 + (lane >> 4) * 4;
#pragma unroll
    for (int r = 0; r < 4; ++r) {
      const int grow = rb + r;
      if (grow < M) {
#pragma unroll
        for (int j = 0; j < 2; ++j)
          Y[(size_t)grow * N + gcolbase + j * 16] = acc[i][j][r] + bias2[j];
      }
    }
  }
}

// ---------------- self-attention: MFMA flash (swapped QK^T), bf16, QB=128 ----------------
// QKV: [MQ, 768] (Q at +0, K at +256, V at +512).
#define QB 128
#define KB 64
#define KP 40   // Ks / P pitch (ushort)
#define VP 72   // Vt pitch (ushort)
__global__ __launch_bounds__(256) void attn_mfma_kernel(
    const float* __restrict__ QKV, float* __restrict__ O)
{
  __shared__ ushort Ks[KB * KP];       // 5120 B
  __shared__ ushort Vt[DH_ * VP];      // 4608 B
  __shared__ ushort Pl[4][32 * KP];    // 10240 B
  const int tid  = threadIdx.x;
  const int lane = tid & 63;
  const int w    = tid >> 6;
  const int bh = blockIdx.y;
  const int h  = bh & (HEADS_ - 1);
  const int b  = bh >> 3;
  const int q0 = blockIdx.x * QB;
  const int lq = lane & 15;
  const int lg = lane >> 4;
  const float scale = 0.17677669529663687f;
  const f32x4 zero4 = {0.f, 0.f, 0.f, 0.f};

  bf16x8 qf[2];
#pragma unroll
  for (int s = 0; s < 2; ++s) {
    int qg = q0 + w * 32 + s * 16 + lq; if (qg > LQ_ - 1) qg = LQ_ - 1;
    const float* qp = QKV + ((size_t)qg * B_ + b) * 768 + h * DH_ + lg * 8;
    const float4 a = *(const float4*)qp;
    const float4 c = *(const float4*)(qp + 4);
    ushort t[8] __attribute__((aligned(16)));
    t[0]=f2bf(a.x*scale); t[1]=f2bf(a.y*scale); t[2]=f2bf(a.z*scale); t[3]=f2bf(a.w*scale);
    t[4]=f2bf(c.x*scale); t[5]=f2bf(c.y*scale); t[6]=f2bf(c.z*scale); t[7]=f2bf(c.w*scale);
    qf[s] = *(const bf16x8*)t;
  }

  float mrow[2] = {-1e30f, -1e30f}, srow[2] = {0.f, 0.f};
  f32x4 oacc[2][2];
  oacc[0][0] = zero4; oacc[0][1] = zero4; oacc[1][0] = zero4; oacc[1][1] = zero4;

  const int nkt = (LQ_ + KB - 1) / KB;   // 15
  for (int t = 0; t < nkt; ++t) {
    const int k0 = t * KB;
    const int klen = (LQ_ - k0) < KB ? (LQ_ - k0) : KB;
    if (t) __syncthreads();
    // ---- stage K ----
    {
      const int kk  = tid >> 2;
      const int dh0 = (tid & 3) * 8;
      ushort kb[8] __attribute__((aligned(16)));
      if (kk < klen) {
        const float* kp = QKV + ((size_t)(k0 + kk) * B_ + b) * 768 + 256 + h * DH_ + dh0;
        const float4 k1 = *(const float4*)kp;
        const float4 k2 = *(const float4*)(kp + 4);
        kb[0]=f2bf(k1.x); kb[1]=f2bf(k1.y); kb[2]=f2bf(k1.z); kb[3]=f2bf(k1.w);
        kb[4]=f2bf(k2.x); kb[5]=f2bf(k2.y); kb[6]=f2bf(k2.z); kb[7]=f2bf(k2.w);
      } else {
#pragma unroll
        for (int j = 0; j < 8; ++j) kb[j] = 0;
      }
      *(bf16x8*)&Ks[kk * KP + dh0] = *(const bf16x8*)kb;
    }
    // ---- stage V transposed (packed u32 writes) ----
    {
      const int kk2  = (tid >> 3) << 1;     // 0,2,..,62
      const int dh0v = (tid & 7) * 4;       // 0,4,..,28
      float v0[4] = {0.f, 0.f, 0.f, 0.f};
      float v1[4] = {0.f, 0.f, 0.f, 0.f};
      if (kk2 < klen) {
        const float4 xx = *(const float4*)(QKV + ((size_t)(k0 + kk2) * B_ + b) * 768 + 512 + h * DH_ + dh0v);
        v0[0] = xx.x; v0[1] = xx.y; v0[2] = xx.z; v0[3] = xx.w;
      }
      if (kk2 + 1 < klen) {
        const float4 xx = *(const float4*)(QKV + ((size_t)(k0 + kk2 + 1) * B_ + b) * 768 + 512 + h * DH_ + dh0v);
        v1[0] = xx.x; v1[1] = xx.y; v1[2] = xx.z; v1[3] = xx.w;
      }
#pragma unroll
      for (int j = 0; j < 4; ++j) {
        const uint pk = (uint)f2bf(v0[j]) | ((uint)f2bf(v1[j]) << 16);
        *(uint*)&Vt[(dh0v + j) * VP + kk2] = pk;
      }
    }
    __syncthreads();

    float cfac[2];
#pragma unroll
    for (int s = 0; s < 2; ++s) {
      f32x4 sc[4];
#pragma unroll
      for (int j = 0; j < 4; ++j) {
        const bf16x8 kf = *(const bf16x8*)&Ks[(j * 16 + lq) * KP + lg * 8];
        sc[j] = __builtin_amdgcn_mfma_f32_16x16x32_bf16(kf, qf[s], zero4, 0, 0, 0);
      }
      if (klen < KB) {
#pragma unroll
        for (int j = 0; j < 4; ++j)
#pragma unroll
          for (int r = 0; r < 4; ++r)
            if (j * 16 + lg * 4 + r >= klen) sc[j][r] = -1e30f;
      }
      float tmax = -1e30f;
#pragma unroll
      for (int j = 0; j < 4; ++j)
#pragma unroll
        for (int r = 0; r < 4; ++r) tmax = fmaxf(tmax, sc[j][r]);
      tmax = fmaxf(tmax, __shfl_xor(tmax, 16, 64));
      tmax = fmaxf(tmax, __shfl_xor(tmax, 32, 64));
      const float mnew = fmaxf(mrow[s], tmax);
      cfac[s] = __expf(mrow[s] - mnew);
      mrow[s] = mnew;
      float tsum = 0.f;
#pragma unroll
      for (int j = 0; j < 4; ++j)
#pragma unroll
        for (int r = 0; r < 4; ++r) {
          const float p = __expf(sc[j][r] - mnew);
          sc[j][r] = p; tsum += p;
        }
      tsum += __shfl_xor(tsum, 16, 64);
      tsum += __shfl_xor(tsum, 32, 64);
      srow[s] = srow[s] * cfac[s] + tsum;
#pragma unroll
      for (int j = 0; j < 4; ++j) {
        const uint lo = (uint)f2bf(sc[j][0]) | ((uint)f2bf(sc[j][1]) << 16);
        const uint hi = (uint)f2bf(sc[j][2]) | ((uint)f2bf(sc[j][3]) << 16);
        *(uint*)&Pl[w][(s * 16 + lq) * KP + j * 16 + lg * 4]     = lo;
        *(uint*)&Pl[w][(s * 16 + lq) * KP + j * 16 + lg * 4 + 2] = hi;
      }
    }
#pragma unroll
    for (int s = 0; s < 2; ++s) {
      float crow[4];
#pragma unroll
      for (int r = 0; r < 4; ++r) crow[r] = __shfl(cfac[s], lg * 4 + r, 64);
#pragma unroll
      for (int nt = 0; nt < 2; ++nt)
#pragma unroll
        for (int r = 0; r < 4; ++r) oacc[s][nt][r] *= crow[r];
#pragma unroll
      for (int ks = 0; ks < 2; ++ks) {
        const bf16x8 pf = *(const bf16x8*)&Pl[w][(s * 16 + lq) * KP + ks * 32 + lg * 8];
#pragma unroll
        for (int nt = 0; nt < 2; ++nt) {
          const bf16x8 vf = *(const bf16x8*)&Vt[(nt * 16 + lq) * VP + ks * 32 + lg * 8];
          oacc[s][nt] = __builtin_amdgcn_mfma_f32_16x16x32_bf16(pf, vf, oacc[s][nt], 0, 0, 0);
        }
      }
    }
  }
#pragma unroll
  for (int s = 0; s < 2; ++s) {
    float sinv[4];
#pragma unroll
    for (int r = 0; r < 4; ++r) {
      const float sr = __shfl(srow[s], lg * 4 + r, 64);
      sinv[r] = 1.f / sr;
    }
#pragma unroll
    for (int r = 0; r < 4; ++r) {
      const int qg = q0 + w * 32 + s * 16 + lg * 4 + r;
      if (qg < LQ_) {
        float* op = O + ((size_t)qg * B_ + b) * 256 + h * DH_;
        op[lq]      = oacc[s][0][r] * sinv[r];
        op[16 + lq] = oacc[s][1][r] * sinv[r];
      }
    }
  }
}

// ---------------- residual + LayerNorm: Y = LN(X + R) * g + b ----------------
__global__ __launch_bounds__(256) void ln_kernel(
    const float* __restrict__ X, const float* __restrict__ R,
    const float* __restrict__ g, const float* __restrict__ be,
    float* __restrict__ Y)
{
  const int row  = blockIdx.x * 4 + (threadIdx.x >> 6);
  const int lane = threadIdx.x & 63;
  const size_t base = (size_t)row * D_ + lane * 4;
  float4 v = *(const float4*)(X + base);
  const float4 rv = *(const float4*)(R + base);
  v.x += rv.x; v.y += rv.y; v.z += rv.z; v.w += rv.w;

  float sum = (v.x + v.y) + (v.z + v.w);
#pragma unroll
  for (int o = 32; o > 0; o >>= 1) sum += __shfl_xor(sum, o, 64);
  const float mean = sum * (1.f / D_);
  const float4 d = make_float4(v.x - mean, v.y - mean, v.z - mean, v.w - mean);
  float sq = (d.x * d.x + d.y * d.y) + (d.z * d.z + d.w * d.w);
#pragma unroll
  for (int o = 32; o > 0; o >>= 1) sq += __shfl_xor(sq, o, 64);
  const float rs = rsqrtf(sq * (1.f / D_) + 1e-5f);

  const float4 gv = *(const float4*)(g + lane * 4);
  const float4 bv = *(const float4*)(be + lane * 4);
  float4 o4;
  o4.x = d.x * rs * gv.x + bv.x;
  o4.y = d.y * rs * gv.y + bv.y;
  o4.z = d.z * rs * gv.z + bv.z;
  o4.w = d.w * rs * gv.w + bv.w;
  *(float4*)(Y + base) = o4;
}

// ---------------- MSDeformAttn sampling (bf16 value; 4 threads per (q,b,h)) ----------------
__global__ __launch_bounds__(256) void msdeform_kernel(
    const float* __restrict__ refp, const float* __restrict__ offb,
    const float* __restrict__ awb, const ushort* __restrict__ value,
    float* __restrict__ out)
{
  const int t  = blockIdx.x * 256 + threadIdx.x;   // < MQ*HEADS_*4
  const int dq = t & 3;            // dh quarter: 8 floats
  const int h  = (t >> 2) & 7;
  const int u  = t >> 5;           // b*LQ_ + q
  const int b  = u / LQ_;
  const int q  = u - b * LQ_;
  const int r  = q * B_ + b;

  float aw[LVLS_ * PTS_];
  const float* ap = awb + (size_t)r * 128 + h * 16;
  float m = -1e30f;
#pragma unroll
  for (int i = 0; i < 16; ++i) { aw[i] = ap[i]; m = fmaxf(m, aw[i]); }
  float s = 0.f;
#pragma unroll
  for (int i = 0; i < 16; ++i) { aw[i] = __expf(aw[i] - m); s += aw[i]; }
  const float inv = 1.f / s;
#pragma unroll
  for (int i = 0; i < 16; ++i) aw[i] *= inv;

  float o[8] = {};
  const int HH[4] = {100, 50, 25, 13};
  const int WW[4] = {100, 50, 25, 13};
  const int ST[4] = {0, 10000, 12500, 13125};
  const float* orow = offb + (size_t)r * 256 + h * (LVLS_ * PTS_ * 2);
  const int dh0 = h * DH_ + dq * 8;

  for (int l = 0; l < LVLS_; ++l) {
    const float4 rf = *(const float4*)(refp + (((size_t)q * B_ + b) * LVLS_ + l) * 4);
    const int W_ = WW[l], H_ = HH[l], s0 = ST[l];
    for (int p = 0; p < PTS_; ++p) {
      const float ox = orow[(l * PTS_ + p) * 2 + 0];
      const float oy = orow[(l * PTS_ + p) * 2 + 1];
      const float lx = rf.x + ox * 0.125f * rf.z;
      const float ly = rf.y + oy * 0.125f * rf.w;
      const float x = lx * W_ - 0.5f;
      const float y = ly * H_ - 0.5f;
      const float x0f = floorf(x), y0f = floorf(y);
      const float wx = x - x0f, wy = y - y0f;
      const int x0 = (int)x0f, y0 = (int)y0f;
      const float a = aw[l * PTS_ + p];
      const float cw[4] = {(1.f - wx) * (1.f - wy) * a, wx * (1.f - wy) * a,
                           (1.f - wx) * wy * a,         wx * wy * a};
      const int cx[4] = {x0, x0 + 1, x0, x0 + 1};
      const int cy[4] = {y0, y0, y0 + 1, y0 + 1};
#pragma unroll
      for (int c = 0; c < 4; ++c) {
        const int xi = cx[c], yi = cy[c];
        if (xi >= 0 && xi < W_ && yi >= 0 && yi < H_) {
          const ushort* vp = value + ((size_t)(s0 + yi * W_ + xi) * B_ + b) * 256 + dh0;
          const float w = cw[c];
          const bf16x8 vv = *(const bf16x8*)vp;   // 16 B
#pragma unroll
          for (int j = 0; j < 8; ++j)
            o[j] = fmaf(w, bf2f(((const ushort*)&vv)[j]), o[j]);
        }
      }
    }
  }
  float* op = out + (size_t)r * 256 + dh0;
  float4 x1; x1.x = o[0]; x1.y = o[1]; x1.z = o[2]; x1.w = o[3];
  float4 x2; x2.x = o[4]; x2.y = o[5]; x2.z = o[6]; x2.w = o[7];
  *(float4*)op = x1;
  *(float4*)(op + 4) = x2;
}

extern "C" void kernel_launch(void* const* d_in, const int* in_sizes, int n_in,
                              void* d_out, int out_size, void* d_ws, size_t ws_size,
                              hipStream_t stream) {
  const float* tgt       = (const float*)d_in[0];
  const float* pos       = (const float*)d_in[1];
  const float* refp      = (const float*)d_in[2];
  const float* memory    = (const float*)d_in[3];
  const float* in_proj_w = (const float*)d_in[6];
  const float* in_proj_b = (const float*)d_in[7];
  const float* sa_out_w  = (const float*)d_in[8];
  const float* sa_out_b  = (const float*)d_in[9];
  const float* off_w     = (const float*)d_in[10];
  const float* off_b     = (const float*)d_in[11];
  const float* aw_w      = (const float*)d_in[12];
  const float* aw_b      = (const float*)d_in[13];
  const float* val_w     = (const float*)d_in[14];
  const float* val_b     = (const float*)d_in[15];
  const float* ca_out_w  = (const float*)d_in[16];
  const float* ca_out_b  = (const float*)d_in[17];
  const float* lin1_w    = (const float*)d_in[18];
  const float* lin1_b    = (const float*)d_in[19];
  const float* lin2_w    = (const float*)d_in[20];
  const float* lin2_b    = (const float*)d_in[21];
  const float* n1g = (const float*)d_in[22];
  const float* n1b = (const float*)d_in[23];
  const float* n2g = (const float*)d_in[24];
  const float* n2b = (const float*)d_in[25];
  const float* n3g = (const float*)d_in[26];
  const float* n3b = (const float*)d_in[27];

  float* ws = (float*)d_ws;
  float* QKV   = ws;                               // MQ*768 (Q|K|V); later reused: offb + awb
  float* Cb    = QKV  + (size_t)MQ * 768;          // MQ*256
  float* Db    = Cb   + (size_t)MQ * 256;          // MQ*256
  float* tgt1  = Db   + (size_t)MQ * 256;          // MQ*256
  float* tgt2  = tgt1 + (size_t)MQ * 256;          // MQ*256
  float* big   = tgt2 + (size_t)MQ * 256;          // max(MV*128, MQ*1024) floats
  ushort* value = (ushort*)big;                    // MV*256 bf16
  float* mid   = big;    // FFN mid aliases value region (disjoint lifetimes)
  float* offb  = QKV;                              // reuse (QKV dead after attn)
  float* awb   = QKV + (size_t)MQ * 256;

  const dim3 blk(256);
  const int gy_q = (MQ + 63) / 64;        // 225
  const int gy_v128 = (MV + 127) / 128;   // 1662
  const int qtiles = (LQ_ + QB - 1) / QB; // 8

  // 1) QKV projection — one N=768 GEMM; pos added only for Q,K columns (n0<512)
  gemm_bf16_64<<<dim3(12, gy_q), blk, 0, stream>>>(tgt, pos, in_proj_w, in_proj_b, QKV, MQ, 768, D_, 0, 0, 512);
  // 2) self-attention — bf16 MFMA flash, QB=128
  attn_mfma_kernel<<<dim3(qtiles, B_ * HEADS_), blk, 0, stream>>>(QKV, Cb);
  // 3) SA out proj
  gemm_bf16_64<<<dim3(4, gy_q), blk, 0, stream>>>(Cb, nullptr, sa_out_w, sa_out_b, Db, MQ, 256, D_, 0, 0, 0);
  // 4) tgt1 = LN(tgt + sa; norm2)
  ln_kernel<<<MQ / 4, blk, 0, stream>>>(tgt, Db, n2g, n2b, tgt1);
  // 5) value projection over memory — global_load_lds staged, bf16 out
  gemm_val_gld<<<dim3(2, gy_v128), dim3(512), 0, stream>>>(memory, val_w, val_b, value, MV);
  // 6) sampling offsets + aw logits — fused dual-W GEMM
  gemm_dual_64<<<dim3(6, gy_q), blk, 0, stream>>>(tgt1, pos, off_w, off_b, offb, 256, 4, aw_w, aw_b, awb, 128, MQ, D_);
  // 7) deformable sampling -> Cb  (bf16 value gather)
  msdeform_kernel<<<(MQ * HEADS_ * 4 + 255) / 256, blk, 0, stream>>>(refp, offb, awb, value, Cb);
  // 8) CA out proj
  gemm_bf16_64<<<dim3(4, gy_q), blk, 0, stream>>>(Cb, nullptr, ca_out_w, ca_out_b, Db, MQ, 256, D_, 0, 0, 0);
  // 9) tgt2 = LN(tgt1 + ca; norm1)
  ln_kernel<<<MQ / 4, blk, 0, stream>>>(tgt1, Db, n1g, n1b, tgt2);
  // 10) FFN lin1 + relu -> mid
  gemm_bf16_64<<<dim3(16, gy_q), blk, 0, stream>>>(tgt2, nullptr, lin1_w, lin1_b, mid, MQ, DFF_, D_, 1, 0, 0);
  // 11) FFN lin2 -> Db
  gemm_bf16_64<<<dim3(4, gy_q), blk, 0, stream>>>(mid, nullptr, lin2_w, lin2_b, Db, MQ, 256, DFF_, 0, 0, 0);
  // 12) out = LN(tgt2 + ffn; norm3)
  ln_kernel<<<MQ / 4, blk, 0, stream>>>(tgt2, Db, n3g, n3b, (float*)d_out);
}

// Round 17
// 498.198 us; speedup vs baseline: 1.1717x; 1.0035x over previous
//
#include <hip/hip_runtime.h>
#include <hip/hip_bf16.h>
#include <math.h>

#define D_ 256
#define HEADS_ 8
#define DH_ 32
#define LVLS_ 4
#define PTS_ 4
#define DFF_ 1024
#define LQ_ 900
#define B_ 16
#define S_ 13294
#define MQ (LQ_*B_)      // 14400
#define MV (S_*B_)       // 212704

typedef __attribute__((ext_vector_type(4))) float f32x4;
typedef __attribute__((ext_vector_type(8))) short bf16x8;

static __device__ inline ushort f2bf(float f) {
  __hip_bfloat16 h = __float2bfloat16(f);   // RNE
  union { __hip_bfloat16 h; ushort u; } c; c.h = h;
  return c.u;
}
static __device__ inline float bf2f(ushort u) {
  union { float f; uint u; } c; c.u = (uint)u << 16; return c.f;
}
static __device__ __forceinline__ void gload16(const float* g, float* lds) {
  __builtin_amdgcn_global_load_lds(
      (const __attribute__((address_space(1))) void*)g,
      (__attribute__((address_space(3))) void*)lds,
      16, 0, 0);
}

#define GP 40   // LDS pitch in ushorts (80 B rows)

// ---------------- value-projection GEMM: counted-vmcnt double-buffer pipeline ----------------
// Y(bf16) = A @ W^T + bias. A:[M,256] f32; W:[256,256] f32. 512 thr, 128x128 tile.
// T4 (counted vmcnt): tile t+1's 4 global_load_lds stay IN FLIGHT across the whole
// of iteration t (compute + both raw barriers); vmcnt is never drained to 0 in the
// steady state. Swizzle identical to R16's verified gemm_val_gld (both-sides XOR).
__global__ __launch_bounds__(512) void gemm_val_pipe(
    const float* __restrict__ A, const float* __restrict__ Wm,
    const float* __restrict__ bias, ushort* __restrict__ Y, int M)
{
  __shared__ float AsF[2][128 * 32];   // 2 x 16 KB
  __shared__ float WsF[2][128 * 32];   // 2 x 16 KB  (64 KB total)
  const int tid  = threadIdx.x;
  const int lane = tid & 63;
  const int wid  = tid >> 6;          // 0..7
  const int wr   = wid >> 1;          // 0..3: 32-row band
  const int wc   = wid & 1;           // 0..1: 64-col half
  const int fr = lane & 15;
  const int lg = lane >> 4;           // 0..3
  const int m0 = blockIdx.y * 128, n0 = blockIdx.x * 128;

  f32x4 acc[2][4];
  const f32x4 zero = {0.f, 0.f, 0.f, 0.f};
#pragma unroll
  for (int i = 0; i < 2; ++i)
#pragma unroll
    for (int j = 0; j < 4; ++j) acc[i][j] = zero;

  // staging lane geometry (per 8-row chunk of 1024 B)
  const int rin   = lane >> 3;              // row in chunk 0..7
  const int colx  = ((lane & 7) ^ rin) * 4; // pre-swizzled source col (f32)
  // fragment read geometry
  const int x  = fr & 7;                    // read-side XOR
  const int sb = lg * 2;                    // base 16B-slot of this lane's k-slice

#define STAGE(p, k0)                                                    \
  {                                                                     \
    _Pragma("unroll")                                                   \
    for (int c2 = 0; c2 < 2; ++c2) {                                    \
      const int c  = (wid << 1) | c2;                                   \
      const int rb = c * 8 + rin;                                       \
      int ar = m0 + rb; if (ar > M - 1) ar = M - 1;                     \
      gload16(A  + (size_t)ar * 256 + (k0) + colx, &AsF[p][c * 256]);   \
      gload16(Wm + (size_t)(n0 + rb) * 256 + (k0) + colx, &WsF[p][c * 256]); \
    }                                                                   \
  }

  // prologue: tiles 0 and 1 in flight; wait only for tile 0 (4 of 8 outstanding)
  STAGE(0, 0);
  STAGE(1, 32);
  asm volatile("s_waitcnt vmcnt(4)" ::: "memory");
  __builtin_amdgcn_sched_barrier(0);
  __builtin_amdgcn_s_barrier();

#pragma unroll
  for (int t = 0; t < 8; ++t) {
    const int p = t & 1;
    // ---- compute tile t from buf p: swizzled f32 reads + cvt + 8 MFMAs ----
    const float* Ab = AsF[p];
    const float* Wb = WsF[p];
    bf16x8 ar8[2], br8[4];
#pragma unroll
    for (int i = 0; i < 2; ++i) {
      const float* base = Ab + (wr * 32 + i * 16 + fr) * 32;
      const float4 lo = *(const float4*)(base + ((sb ^ x) << 2));
      const float4 hi = *(const float4*)(base + (((sb + 1) ^ x) << 2));
      ushort tt[8] __attribute__((aligned(16)));
      tt[0]=f2bf(lo.x); tt[1]=f2bf(lo.y); tt[2]=f2bf(lo.z); tt[3]=f2bf(lo.w);
      tt[4]=f2bf(hi.x); tt[5]=f2bf(hi.y); tt[6]=f2bf(hi.z); tt[7]=f2bf(hi.w);
      ar8[i] = *(const bf16x8*)tt;
    }
#pragma unroll
    for (int j = 0; j < 4; ++j) {
      const float* base = Wb + (wc * 64 + j * 16 + fr) * 32;
      const float4 lo = *(const float4*)(base + ((sb ^ x) << 2));
      const float4 hi = *(const float4*)(base + (((sb + 1) ^ x) << 2));
      ushort tt[8] __attribute__((aligned(16)));
      tt[0]=f2bf(lo.x); tt[1]=f2bf(lo.y); tt[2]=f2bf(lo.z); tt[3]=f2bf(lo.w);
      tt[4]=f2bf(hi.x); tt[5]=f2bf(hi.y); tt[6]=f2bf(hi.z); tt[7]=f2bf(hi.w);
      br8[j] = *(const bf16x8*)tt;
    }
#pragma unroll
    for (int i = 0; i < 2; ++i)
#pragma unroll
      for (int j = 0; j < 4; ++j)
        acc[i][j] = __builtin_amdgcn_mfma_f32_16x16x32_bf16(ar8[i], br8[j], acc[i][j], 0, 0, 0);

    if (t == 7) break;
    // ---- all waves finished reading buf p before it is refilled ----
    __builtin_amdgcn_sched_barrier(0);
    __builtin_amdgcn_s_barrier();
    if (t + 2 < 8) {
      STAGE(p, (t + 2) * 32);                            // refill buf p with tile t+2
      asm volatile("s_waitcnt vmcnt(4)" ::: "memory");   // tile t+1 landed; t+2 in flight
    } else {
      asm volatile("s_waitcnt vmcnt(0)" ::: "memory");   // drain final tile
    }
    __builtin_amdgcn_sched_barrier(0);
    __builtin_amdgcn_s_barrier();                        // tile t+1 visible to all waves
  }
#undef STAGE

  // epilogue: C/D layout col = lane&15, row = (lane>>4)*4 + reg; bf16 out
  const int gcolbase = n0 + wc * 64 + fr;
  float bias4[4];
#pragma unroll
  for (int j = 0; j < 4; ++j) bias4[j] = bias[gcolbase + j * 16];
#pragma unroll
  for (int i = 0; i < 2; ++i) {
    const int rb = m0 + wr * 32 + i * 16 + lg * 4;
#pragma unroll
    for (int r = 0; r < 4; ++r) {
      const int grow = rb + r;
      if (grow < M) {
#pragma unroll
        for (int j = 0; j < 4; ++j)
          Y[(size_t)grow * 256 + gcolbase + j * 16] = f2bf(acc[i][j][r] + bias4[j]);
      }
    }
  }
}

// ---------------- bf16-MFMA GEMM, 64x64 tile ----------------
// x2_nlim: add X2 to the A-tile only for blocks with n0 < x2_nlim.
__global__ __launch_bounds__(256) void gemm_bf16_64(
    const float* __restrict__ A, const float* __restrict__ X2,
    const float* __restrict__ Wm, const float* __restrict__ bias,
    float* __restrict__ Y, int M, int N, int K, int relu, int outbf, int x2_nlim)
{
  __shared__ ushort As[64 * GP];   // 5 KB
  __shared__ ushort Ws[64 * GP];   // 5 KB
  const int tid  = threadIdx.x;
  const int lane = tid & 63;
  const int wid  = tid >> 6;
  const int wr = wid >> 1, wc = wid & 1;
  const int fr = lane & 15;
  const int fk = (lane >> 4) << 3;
  const int m0 = blockIdx.y * 64, n0 = blockIdx.x * 64;

  f32x4 acc[2][2];
  const f32x4 zero = {0.f, 0.f, 0.f, 0.f};
#pragma unroll
  for (int i = 0; i < 2; ++i)
#pragma unroll
    for (int j = 0; j < 2; ++j) acc[i][j] = zero;

  const int srow = tid >> 1;          // 0..127
  const int skh  = (tid & 1) << 4;    // 0 or 16
  const bool isA = srow < 64;
  const float* src;
  const float* src2 = nullptr;
  ushort* dst;
  if (isA) {
    int gr = m0 + srow; if (gr > M - 1) gr = M - 1;
    src = A + (size_t)gr * K + skh;
    if (X2 && n0 < x2_nlim) src2 = X2 + (size_t)gr * K + skh;
    dst = &As[srow * GP + skh];
  } else {
    src = Wm + (size_t)(n0 + srow - 64) * K + skh;
    dst = &Ws[(srow - 64) * GP + skh];
  }

  float4 pd[4];
#pragma unroll
  for (int i2 = 0; i2 < 4; ++i2) pd[i2] = *(const float4*)(src + i2 * 4);
  if (src2) {
#pragma unroll
    for (int i2 = 0; i2 < 4; ++i2) {
      const float4 u = *(const float4*)(src2 + i2 * 4);
      pd[i2].x += u.x; pd[i2].y += u.y; pd[i2].z += u.z; pd[i2].w += u.w;
    }
  }

  for (int k0 = 0; k0 < K; k0 += 32) {
    if (k0) __syncthreads();
    ushort tmp[16] __attribute__((aligned(16)));
#pragma unroll
    for (int i2 = 0; i2 < 4; ++i2) {
      tmp[i2*4+0] = f2bf(pd[i2].x); tmp[i2*4+1] = f2bf(pd[i2].y);
      tmp[i2*4+2] = f2bf(pd[i2].z); tmp[i2*4+3] = f2bf(pd[i2].w);
    }
    *(bf16x8*)(dst)     = *(const bf16x8*)&tmp[0];
    *(bf16x8*)(dst + 8) = *(const bf16x8*)&tmp[8];
    if (k0 + 32 < K) {
      const float* s = src + k0 + 32;
#pragma unroll
      for (int i2 = 0; i2 < 4; ++i2) pd[i2] = *(const float4*)(s + i2 * 4);
      if (src2) {
        const float* s2 = src2 + k0 + 32;
#pragma unroll
        for (int i2 = 0; i2 < 4; ++i2) {
          const float4 u = *(const float4*)(s2 + i2 * 4);
          pd[i2].x += u.x; pd[i2].y += u.y; pd[i2].z += u.z; pd[i2].w += u.w;
        }
      }
    }
    __syncthreads();

    bf16x8 af[2], bf[2];
#pragma unroll
    for (int i = 0; i < 2; ++i)
      af[i] = *(const bf16x8*)&As[(wr*32 + i*16 + fr)*GP + fk];
#pragma unroll
    for (int j = 0; j < 2; ++j)
      bf[j] = *(const bf16x8*)&Ws[(wc*32 + j*16 + fr)*GP + fk];
#pragma unroll
    for (int i = 0; i < 2; ++i)
#pragma unroll
      for (int j = 0; j < 2; ++j)
        acc[i][j] = __builtin_amdgcn_mfma_f32_16x16x32_bf16(af[i], bf[j], acc[i][j], 0, 0, 0);
  }

  const int gcolbase = n0 + wc * 32 + fr;
  float bias2[2];
#pragma unroll
  for (int j = 0; j < 2; ++j) bias2[j] = bias[gcolbase + j * 16];
#pragma unroll
  for (int i = 0; i < 2; ++i) {
    const int rb = m0 + wr * 32 + i * 16 + (lane >> 4) * 4;
#pragma unroll
    for (int r = 0; r < 4; ++r) {
      const int grow = rb + r;
      if (grow < M) {
#pragma unroll
        for (int j = 0; j < 2; ++j) {
          float v = acc[i][j][r] + bias2[j];
          if (relu) v = fmaxf(v, 0.f);
          if (outbf) ((ushort*)Y)[(size_t)grow * N + gcolbase + j * 16] = f2bf(v);
          else       Y[(size_t)grow * N + gcolbase + j * 16] = v;
        }
      }
    }
  }
}

// ---------------- dual-W bf16 GEMM, 64x64 tile ----------------
__global__ __launch_bounds__(256) void gemm_dual_64(
    const float* __restrict__ A, const float* __restrict__ X2,
    const float* __restrict__ W1, const float* __restrict__ b1,
    float* __restrict__ Y1, int N1, int nb1,
    const float* __restrict__ W2, const float* __restrict__ b2,
    float* __restrict__ Y2, int N2, int M, int K)
{
  __shared__ ushort As[64 * GP];
  __shared__ ushort Ws[64 * GP];
  const int tid  = threadIdx.x;
  const int lane = tid & 63;
  const int wid  = tid >> 6;
  const int wr = wid >> 1, wc = wid & 1;
  const int fr = lane & 15;
  const int fk = (lane >> 4) << 3;
  const int bx = blockIdx.x;
  const bool second = bx >= nb1;
  const float* Wm  = second ? W2 : W1;
  const float* bia = second ? b2 : b1;
  float* Y         = second ? Y2 : Y1;
  const int N      = second ? N2 : N1;
  const int n0     = (second ? (bx - nb1) : bx) * 64;
  const int m0     = blockIdx.y * 64;

  f32x4 acc[2][2];
  const f32x4 zero = {0.f, 0.f, 0.f, 0.f};
#pragma unroll
  for (int i = 0; i < 2; ++i)
#pragma unroll
    for (int j = 0; j < 2; ++j) acc[i][j] = zero;

  const int srow = tid >> 1;
  const int skh  = (tid & 1) << 4;
  const bool isA = srow < 64;
  const float* src;
  const float* src2 = nullptr;
  ushort* dst;
  if (isA) {
    int gr = m0 + srow; if (gr > M - 1) gr = M - 1;
    src = A + (size_t)gr * K + skh;
    if (X2) src2 = X2 + (size_t)gr * K + skh;
    dst = &As[srow * GP + skh];
  } else {
    src = Wm + (size_t)(n0 + srow - 64) * K + skh;
    dst = &Ws[(srow - 64) * GP + skh];
  }

  float4 pd[4];
#pragma unroll
  for (int i2 = 0; i2 < 4; ++i2) pd[i2] = *(const float4*)(src + i2 * 4);
  if (src2) {
#pragma unroll
    for (int i2 = 0; i2 < 4; ++i2) {
      const float4 u = *(const float4*)(src2 + i2 * 4);
      pd[i2].x += u.x; pd[i2].y += u.y; pd[i2].z += u.z; pd[i2].w += u.w;
    }
  }

  for (int k0 = 0; k0 < K; k0 += 32) {
    if (k0) __syncthreads();
    ushort tmp[16] __attribute__((aligned(16)));
#pragma unroll
    for (int i2 = 0; i2 < 4; ++i2) {
      tmp[i2*4+0] = f2bf(pd[i2].x); tmp[i2*4+1] = f2bf(pd[i2].y);
      tmp[i2*4+2] = f2bf(pd[i2].z); tmp[i2*4+3] = f2bf(pd[i2].w);
    }
    *(bf16x8*)(dst)     = *(const bf16x8*)&tmp[0];
    *(bf16x8*)(dst + 8) = *(const bf16x8*)&tmp[8];
    if (k0 + 32 < K) {
      const float* s = src + k0 + 32;
#pragma unroll
      for (int i2 = 0; i2 < 4; ++i2) pd[i2] = *(const float4*)(s + i2 * 4);
      if (src2) {
        const float* s2 = src2 + k0 + 32;
#pragma unroll
        for (int i2 = 0; i2 < 4; ++i2) {
          const float4 u = *(const float4*)(s2 + i2 * 4);
          pd[i2].x += u.x; pd[i2].y += u.y; pd[i2].z += u.z; pd[i2].w += u.w;
        }
      }
    }
    __syncthreads();

    bf16x8 af[2], bf[2];
#pragma unroll
    for (int i = 0; i < 2; ++i)
      af[i] = *(const bf16x8*)&As[(wr*32 + i*16 + fr)*GP + fk];
#pragma unroll
    for (int j = 0; j < 2; ++j)
      bf[j] = *(const bf16x8*)&Ws[(wc*32 + j*16 + fr)*GP + fk];
#pragma unroll
    for (int i = 0; i < 2; ++i)
#pragma unroll
      for (int j = 0; j < 2; ++j)
        acc[i][j] = __builtin_amdgcn_mfma_f32_16x16x32_bf16(af[i], bf[j], acc[i][j], 0, 0, 0);
  }

  const int gcolbase = n0 + wc * 32 + fr;
  float bias2[2];
#pragma unroll
  for (int j = 0; j < 2; ++j) bias2[j] = bia[gcolbase + j * 16];
#pragma unroll
  for (int i = 0; i < 2; ++i) {
    const int rb = m0 + wr * 32 + i * 16 + (lane >> 4) * 4;
#pragma unroll
    for (int r = 0; r < 4; ++r) {
      const int grow = rb + r;
      if (grow < M) {
#pragma unroll
        for (int j = 0; j < 2; ++j)
          Y[(size_t)grow * N + gcolbase + j * 16] = acc[i][j][r] + bias2[j];
      }
    }
  }
}

// ---------------- self-attention: MFMA flash (swapped QK^T), bf16, QB=128 ----------------
// QKV: [MQ, 768] (Q at +0, K at +256, V at +512).
#define QB 128
#define KB 64
#define KP 40   // Ks / P pitch (ushort)
#define VP 72   // Vt pitch (ushort)
__global__ __launch_bounds__(256) void attn_mfma_kernel(
    const float* __restrict__ QKV, float* __restrict__ O)
{
  __shared__ ushort Ks[KB * KP];       // 5120 B
  __shared__ ushort Vt[DH_ * VP];      // 4608 B
  __shared__ ushort Pl[4][32 * KP];    // 10240 B
  const int tid  = threadIdx.x;
  const int lane = tid & 63;
  const int w    = tid >> 6;
  const int bh = blockIdx.y;
  const int h  = bh & (HEADS_ - 1);
  const int b  = bh >> 3;
  const int q0 = blockIdx.x * QB;
  const int lq = lane & 15;
  const int lg = lane >> 4;
  const float scale = 0.17677669529663687f;
  const f32x4 zero4 = {0.f, 0.f, 0.f, 0.f};

  bf16x8 qf[2];
#pragma unroll
  for (int s = 0; s < 2; ++s) {
    int qg = q0 + w * 32 + s * 16 + lq; if (qg > LQ_ - 1) qg = LQ_ - 1;
    const float* qp = QKV + ((size_t)qg * B_ + b) * 768 + h * DH_ + lg * 8;
    const float4 a = *(const float4*)qp;
    const float4 c = *(const float4*)(qp + 4);
    ushort t[8] __attribute__((aligned(16)));
    t[0]=f2bf(a.x*scale); t[1]=f2bf(a.y*scale); t[2]=f2bf(a.z*scale); t[3]=f2bf(a.w*scale);
    t[4]=f2bf(c.x*scale); t[5]=f2bf(c.y*scale); t[6]=f2bf(c.z*scale); t[7]=f2bf(c.w*scale);
    qf[s] = *(const bf16x8*)t;
  }

  float mrow[2] = {-1e30f, -1e30f}, srow[2] = {0.f, 0.f};
  f32x4 oacc[2][2];
  oacc[0][0] = zero4; oacc[0][1] = zero4; oacc[1][0] = zero4; oacc[1][1] = zero4;

  const int nkt = (LQ_ + KB - 1) / KB;   // 15
  for (int t = 0; t < nkt; ++t) {
    const int k0 = t * KB;
    const int klen = (LQ_ - k0) < KB ? (LQ_ - k0) : KB;
    if (t) __syncthreads();
    // ---- stage K ----
    {
      const int kk  = tid >> 2;
      const int dh0 = (tid & 3) * 8;
      ushort kb[8] __attribute__((aligned(16)));
      if (kk < klen) {
        const float* kp = QKV + ((size_t)(k0 + kk) * B_ + b) * 768 + 256 + h * DH_ + dh0;
        const float4 k1 = *(const float4*)kp;
        const float4 k2 = *(const float4*)(kp + 4);
        kb[0]=f2bf(k1.x); kb[1]=f2bf(k1.y); kb[2]=f2bf(k1.z); kb[3]=f2bf(k1.w);
        kb[4]=f2bf(k2.x); kb[5]=f2bf(k2.y); kb[6]=f2bf(k2.z); kb[7]=f2bf(k2.w);
      } else {
#pragma unroll
        for (int j = 0; j < 8; ++j) kb[j] = 0;
      }
      *(bf16x8*)&Ks[kk * KP + dh0] = *(const bf16x8*)kb;
    }
    // ---- stage V transposed (packed u32 writes) ----
    {
      const int kk2  = (tid >> 3) << 1;     // 0,2,..,62
      const int dh0v = (tid & 7) * 4;       // 0,4,..,28
      float v0[4] = {0.f, 0.f, 0.f, 0.f};
      float v1[4] = {0.f, 0.f, 0.f, 0.f};
      if (kk2 < klen) {
        const float4 xx = *(const float4*)(QKV + ((size_t)(k0 + kk2) * B_ + b) * 768 + 512 + h * DH_ + dh0v);
        v0[0] = xx.x; v0[1] = xx.y; v0[2] = xx.z; v0[3] = xx.w;
      }
      if (kk2 + 1 < klen) {
        const float4 xx = *(const float4*)(QKV + ((size_t)(k0 + kk2 + 1) * B_ + b) * 768 + 512 + h * DH_ + dh0v);
        v1[0] = xx.x; v1[1] = xx.y; v1[2] = xx.z; v1[3] = xx.w;
      }
#pragma unroll
      for (int j = 0; j < 4; ++j) {
        const uint pk = (uint)f2bf(v0[j]) | ((uint)f2bf(v1[j]) << 16);
        *(uint*)&Vt[(dh0v + j) * VP + kk2] = pk;
      }
    }
    __syncthreads();

    float cfac[2];
#pragma unroll
    for (int s = 0; s < 2; ++s) {
      f32x4 sc[4];
#pragma unroll
      for (int j = 0; j < 4; ++j) {
        const bf16x8 kf = *(const bf16x8*)&Ks[(j * 16 + lq) * KP + lg * 8];
        sc[j] = __builtin_amdgcn_mfma_f32_16x16x32_bf16(kf, qf[s], zero4, 0, 0, 0);
      }
      if (klen < KB) {
#pragma unroll
        for (int j = 0; j < 4; ++j)
#pragma unroll
          for (int r = 0; r < 4; ++r)
            if (j * 16 + lg * 4 + r >= klen) sc[j][r] = -1e30f;
      }
      float tmax = -1e30f;
#pragma unroll
      for (int j = 0; j < 4; ++j)
#pragma unroll
        for (int r = 0; r < 4; ++r) tmax = fmaxf(tmax, sc[j][r]);
      tmax = fmaxf(tmax, __shfl_xor(tmax, 16, 64));
      tmax = fmaxf(tmax, __shfl_xor(tmax, 32, 64));
      const float mnew = fmaxf(mrow[s], tmax);
      cfac[s] = __expf(mrow[s] - mnew);
      mrow[s] = mnew;
      float tsum = 0.f;
#pragma unroll
      for (int j = 0; j < 4; ++j)
#pragma unroll
        for (int r = 0; r < 4; ++r) {
          const float p = __expf(sc[j][r] - mnew);
          sc[j][r] = p; tsum += p;
        }
      tsum += __shfl_xor(tsum, 16, 64);
      tsum += __shfl_xor(tsum, 32, 64);
      srow[s] = srow[s] * cfac[s] + tsum;
#pragma unroll
      for (int j = 0; j < 4; ++j) {
        const uint lo = (uint)f2bf(sc[j][0]) | ((uint)f2bf(sc[j][1]) << 16);
        const uint hi = (uint)f2bf(sc[j][2]) | ((uint)f2bf(sc[j][3]) << 16);
        *(uint*)&Pl[w][(s * 16 + lq) * KP + j * 16 + lg * 4]     = lo;
        *(uint*)&Pl[w][(s * 16 + lq) * KP + j * 16 + lg * 4 + 2] = hi;
      }
    }
#pragma unroll
    for (int s = 0; s < 2; ++s) {
      float crow[4];
#pragma unroll
      for (int r = 0; r < 4; ++r) crow[r] = __shfl(cfac[s], lg * 4 + r, 64);
#pragma unroll
      for (int nt = 0; nt < 2; ++nt)
#pragma unroll
        for (int r = 0; r < 4; ++r) oacc[s][nt][r] *= crow[r];
#pragma unroll
      for (int ks = 0; ks < 2; ++ks) {
        const bf16x8 pf = *(const bf16x8*)&Pl[w][(s * 16 + lq) * KP + ks * 32 + lg * 8];
#pragma unroll
        for (int nt = 0; nt < 2; ++nt) {
          const bf16x8 vf = *(const bf16x8*)&Vt[(nt * 16 + lq) * VP + ks * 32 + lg * 8];
          oacc[s][nt] = __builtin_amdgcn_mfma_f32_16x16x32_bf16(pf, vf, oacc[s][nt], 0, 0, 0);
        }
      }
    }
  }
#pragma unroll
  for (int s = 0; s < 2; ++s) {
    float sinv[4];
#pragma unroll
    for (int r = 0; r < 4; ++r) {
      const float sr = __shfl(srow[s], lg * 4 + r, 64);
      sinv[r] = 1.f / sr;
    }
#pragma unroll
    for (int r = 0; r < 4; ++r) {
      const int qg = q0 + w * 32 + s * 16 + lg * 4 + r;
      if (qg < LQ_) {
        float* op = O + ((size_t)qg * B_ + b) * 256 + h * DH_;
        op[lq]      = oacc[s][0][r] * sinv[r];
        op[16 + lq] = oacc[s][1][r] * sinv[r];
      }
    }
  }
}

// ---------------- residual + LayerNorm: Y = LN(X + R) * g + b ----------------
__global__ __launch_bounds__(256) void ln_kernel(
    const float* __restrict__ X, const float* __restrict__ R,
    const float* __restrict__ g, const float* __restrict__ be,
    float* __restrict__ Y)
{
  const int row  = blockIdx.x * 4 + (threadIdx.x >> 6);
  const int lane = threadIdx.x & 63;
  const size_t base = (size_t)row * D_ + lane * 4;
  float4 v = *(const float4*)(X + base);
  const float4 rv = *(const float4*)(R + base);
  v.x += rv.x; v.y += rv.y; v.z += rv.z; v.w += rv.w;

  float sum = (v.x + v.y) + (v.z + v.w);
#pragma unroll
  for (int o = 32; o > 0; o >>= 1) sum += __shfl_xor(sum, o, 64);
  const float mean = sum * (1.f / D_);
  const float4 d = make_float4(v.x - mean, v.y - mean, v.z - mean, v.w - mean);
  float sq = (d.x * d.x + d.y * d.y) + (d.z * d.z + d.w * d.w);
#pragma unroll
  for (int o = 32; o > 0; o >>= 1) sq += __shfl_xor(sq, o, 64);
  const float rs = rsqrtf(sq * (1.f / D_) + 1e-5f);

  const float4 gv = *(const float4*)(g + lane * 4);
  const float4 bv = *(const float4*)(be + lane * 4);
  float4 o4;
  o4.x = d.x * rs * gv.x + bv.x;
  o4.y = d.y * rs * gv.y + bv.y;
  o4.z = d.z * rs * gv.z + bv.z;
  o4.w = d.w * rs * gv.w + bv.w;
  *(float4*)(Y + base) = o4;
}

// ---------------- MSDeformAttn sampling (bf16 value; 4 threads per (q,b,h)) ----------------
__global__ __launch_bounds__(256) void msdeform_kernel(
    const float* __restrict__ refp, const float* __restrict__ offb,
    const float* __restrict__ awb, const ushort* __restrict__ value,
    float* __restrict__ out)
{
  const int t  = blockIdx.x * 256 + threadIdx.x;   // < MQ*HEADS_*4
  const int dq = t & 3;            // dh quarter: 8 floats
  const int h  = (t >> 2) & 7;
  const int u  = t >> 5;           // b*LQ_ + q
  const int b  = u / LQ_;
  const int q  = u - b * LQ_;
  const int r  = q * B_ + b;

  float aw[LVLS_ * PTS_];
  const float* ap = awb + (size_t)r * 128 + h * 16;
  float m = -1e30f;
#pragma unroll
  for (int i = 0; i < 16; ++i) { aw[i] = ap[i]; m = fmaxf(m, aw[i]); }
  float s = 0.f;
#pragma unroll
  for (int i = 0; i < 16; ++i) { aw[i] = __expf(aw[i] - m); s += aw[i]; }
  const float inv = 1.f / s;
#pragma unroll
  for (int i = 0; i < 16; ++i) aw[i] *= inv;

  float o[8] = {};
  const int HH[4] = {100, 50, 25, 13};
  const int WW[4] = {100, 50, 25, 13};
  const int ST[4] = {0, 10000, 12500, 13125};
  const float* orow = offb + (size_t)r * 256 + h * (LVLS_ * PTS_ * 2);
  const int dh0 = h * DH_ + dq * 8;

  for (int l = 0; l < LVLS_; ++l) {
    const float4 rf = *(const float4*)(refp + (((size_t)q * B_ + b) * LVLS_ + l) * 4);
    const int W_ = WW[l], H_ = HH[l], s0 = ST[l];
    for (int p = 0; p < PTS_; ++p) {
      const float ox = orow[(l * PTS_ + p) * 2 + 0];
      const float oy = orow[(l * PTS_ + p) * 2 + 1];
      const float lx = rf.x + ox * 0.125f * rf.z;
      const float ly = rf.y + oy * 0.125f * rf.w;
      const float x = lx * W_ - 0.5f;
      const float y = ly * H_ - 0.5f;
      const float x0f = floorf(x), y0f = floorf(y);
      const float wx = x - x0f, wy = y - y0f;
      const int x0 = (int)x0f, y0 = (int)y0f;
      const float a = aw[l * PTS_ + p];
      const float cw[4] = {(1.f - wx) * (1.f - wy) * a, wx * (1.f - wy) * a,
                           (1.f - wx) * wy * a,         wx * wy * a};
      const int cx[4] = {x0, x0 + 1, x0, x0 + 1};
      const int cy[4] = {y0, y0, y0 + 1, y0 + 1};
#pragma unroll
      for (int c = 0; c < 4; ++c) {
        const int xi = cx[c], yi = cy[c];
        if (xi >= 0 && xi < W_ && yi >= 0 && yi < H_) {
          const ushort* vp = value + ((size_t)(s0 + yi * W_ + xi) * B_ + b) * 256 + dh0;
          const float w = cw[c];
          const bf16x8 vv = *(const bf16x8*)vp;   // 16 B
#pragma unroll
          for (int j = 0; j < 8; ++j)
            o[j] = fmaf(w, bf2f(((const ushort*)&vv)[j]), o[j]);
        }
      }
    }
  }
  float* op = out + (size_t)r * 256 + dh0;
  float4 x1; x1.x = o[0]; x1.y = o[1]; x1.z = o[2]; x1.w = o[3];
  float4 x2; x2.x = o[4]; x2.y = o[5]; x2.z = o[6]; x2.w = o[7];
  *(float4*)op = x1;
  *(float4*)(op + 4) = x2;
}

extern "C" void kernel_launch(void* const* d_in, const int* in_sizes, int n_in,
                              void* d_out, int out_size, void* d_ws, size_t ws_size,
                              hipStream_t stream) {
  const float* tgt       = (const float*)d_in[0];
  const float* pos       = (const float*)d_in[1];
  const float* refp      = (const float*)d_in[2];
  const float* memory    = (const float*)d_in[3];
  const float* in_proj_w = (const float*)d_in[6];
  const float* in_proj_b = (const float*)d_in[7];
  const float* sa_out_w  = (const float*)d_in[8];
  const float* sa_out_b  = (const float*)d_in[9];
  const float* off_w     = (const float*)d_in[10];
  const float* off_b     = (const float*)d_in[11];
  const float* aw_w      = (const float*)d_in[12];
  const float* aw_b      = (const float*)d_in[13];
  const float* val_w     = (const float*)d_in[14];
  const float* val_b     = (const float*)d_in[15];
  const float* ca_out_w  = (const float*)d_in[16];
  const float* ca_out_b  = (const float*)d_in[17];
  const float* lin1_w    = (const float*)d_in[18];
  const float* lin1_b    = (const float*)d_in[19];
  const float* lin2_w    = (const float*)d_in[20];
  const float* lin2_b    = (const float*)d_in[21];
  const float* n1g = (const float*)d_in[22];
  const float* n1b = (const float*)d_in[23];
  const float* n2g = (const float*)d_in[24];
  const float* n2b = (const float*)d_in[25];
  const float* n3g = (const float*)d_in[26];
  const float* n3b = (const float*)d_in[27];

  float* ws = (float*)d_ws;
  float* QKV   = ws;                               // MQ*768 (Q|K|V); later reused: offb + awb
  float* Cb    = QKV  + (size_t)MQ * 768;          // MQ*256
  float* Db    = Cb   + (size_t)MQ * 256;          // MQ*256
  float* tgt1  = Db   + (size_t)MQ * 256;          // MQ*256
  float* tgt2  = tgt1 + (size_t)MQ * 256;          // MQ*256
  float* big   = tgt2 + (size_t)MQ * 256;          // max(MV*128, MQ*1024) floats
  ushort* value = (ushort*)big;                    // MV*256 bf16
  float* mid   = big;    // FFN mid aliases value region (disjoint lifetimes)
  float* offb  = QKV;                              // reuse (QKV dead after attn)
  float* awb   = QKV + (size_t)MQ * 256;

  const dim3 blk(256);
  const int gy_q = (MQ + 63) / 64;        // 225
  const int gy_v128 = (MV + 127) / 128;   // 1662
  const int qtiles = (LQ_ + QB - 1) / QB; // 8

  // 1) QKV projection — one N=768 GEMM; pos added only for Q,K columns (n0<512)
  gemm_bf16_64<<<dim3(12, gy_q), blk, 0, stream>>>(tgt, pos, in_proj_w, in_proj_b, QKV, MQ, 768, D_, 0, 0, 512);
  // 2) self-attention — bf16 MFMA flash, QB=128
  attn_mfma_kernel<<<dim3(qtiles, B_ * HEADS_), blk, 0, stream>>>(QKV, Cb);
  // 3) SA out proj
  gemm_bf16_64<<<dim3(4, gy_q), blk, 0, stream>>>(Cb, nullptr, sa_out_w, sa_out_b, Db, MQ, 256, D_, 0, 0, 0);
  // 4) tgt1 = LN(tgt + sa; norm2)
  ln_kernel<<<MQ / 4, blk, 0, stream>>>(tgt, Db, n2g, n2b, tgt1);
  // 5) value projection over memory — counted-vmcnt double-buffer pipeline, bf16 out
  gemm_val_pipe<<<dim3(2, gy_v128), dim3(512), 0, stream>>>(memory, val_w, val_b, value, MV);
  // 6) sampling offsets + aw logits — fused dual-W GEMM
  gemm_dual_64<<<dim3(6, gy_q), blk, 0, stream>>>(tgt1, pos, off_w, off_b, offb, 256, 4, aw_w, aw_b, awb, 128, MQ, D_);
  // 7) deformable sampling -> Cb  (bf16 value gather)
  msdeform_kernel<<<(MQ * HEADS_ * 4 + 255) / 256, blk, 0, stream>>>(refp, offb, awb, value, Cb);
  // 8) CA out proj
  gemm_bf16_64<<<dim3(4, gy_q), blk, 0, stream>>>(Cb, nullptr, ca_out_w, ca_out_b, Db, MQ, 256, D_, 0, 0, 0);
  // 9) tgt2 = LN(tgt1 + ca; norm1)
  ln_kernel<<<MQ / 4, blk, 0, stream>>>(tgt1, Db, n1g, n1b, tgt2);
  // 10) FFN lin1 + relu -> mid
  gemm_bf16_64<<<dim3(16, gy_q), blk, 0, stream>>>(tgt2, nullptr, lin1_w, lin1_b, mid, MQ, DFF_, D_, 1, 0, 0);
  // 11) FFN lin2 -> Db
  gemm_bf16_64<<<dim3(4, gy_q), blk, 0, stream>>>(mid, nullptr, lin2_w, lin2_b, Db, MQ, 256, DFF_, 0, 0, 0);
  // 12) out = LN(tgt2 + ffn; norm3)
  ln_kernel<<<MQ / 4, blk, 0, stream>>>(tgt2, Db, n3g, n3b, (float*)d_out);
}